// Round 2
// baseline (773.254 us; speedup 1.0000x reference)
//
#include <hip/hip_runtime.h>
#include <hip/hip_bf16.h>

typedef unsigned short u16;
typedef __attribute__((ext_vector_type(4))) float f32x4;
typedef __attribute__((ext_vector_type(8))) __bf16 bf16x8;

#define DEVI static __device__ __forceinline__

DEVI u16 f2bf(float f) {
    union { float f; unsigned u; } v; v.f = f;
    unsigned r = v.u + 0x7fffu + ((v.u >> 16) & 1u);
    return (u16)(r >> 16);
}

// ---------------- Kernel 1: GroupNorm stats (mean, rstd per (b,g)) ----------
__global__ void __launch_bounds__(256) gn_stats_k(const float* __restrict__ x,
                                                  float* __restrict__ stats) {
    int bg = blockIdx.x;  // 0..31  (b*8+g), group = 32 ch * 4096 = 131072 elems
    const float4* p = reinterpret_cast<const float4*>(x + (size_t)bg * 131072);
    float s = 0.f, s2 = 0.f;
    for (int i = threadIdx.x; i < 32768; i += 256) {
        float4 v = p[i];
        s  += v.x + v.y + v.z + v.w;
        s2 += v.x * v.x + v.y * v.y + v.z * v.z + v.w * v.w;
    }
    for (int off = 32; off; off >>= 1) {
        s  += __shfl_down(s,  off, 64);
        s2 += __shfl_down(s2, off, 64);
    }
    __shared__ float sb[8];
    int w = threadIdx.x >> 6, l = threadIdx.x & 63;
    if (l == 0) { sb[w] = s; sb[4 + w] = s2; }
    __syncthreads();
    if (threadIdx.x == 0) {
        float ts  = sb[0] + sb[1] + sb[2] + sb[3];
        float ts2 = sb[4] + sb[5] + sb[6] + sb[7];
        float mu  = ts * (1.f / 131072.f);
        float var = ts2 * (1.f / 131072.f) - mu * mu;
        stats[bg * 2]     = mu;
        stats[bg * 2 + 1] = rsqrtf(var + 1e-5f);
    }
}

// ---------------- Kernel 2: weights fp32 -> bf16 ----------------------------
__global__ void __launch_bounds__(256) convw_k(const float* __restrict__ qw,
                                               const float* __restrict__ pw,
                                               u16* __restrict__ wq,
                                               u16* __restrict__ wp) {
    int i = blockIdx.x * 256 + threadIdx.x;
    if (i < 196608) wq[i] = f2bf(qw[i]);
    if (i < 65536)  wp[i] = f2bf(pw[i]);
}

// ---------------- Kernel 3: normalize + transpose -> xnT[b][n][c] bf16 ------
__global__ void __launch_bounds__(256) gnorm_t_k(const float* __restrict__ x,
                                                 const float* __restrict__ stats,
                                                 const float* __restrict__ gw,
                                                 const float* __restrict__ gb,
                                                 u16* __restrict__ xnT) {
    __shared__ float tile[32][33];
    int b = blockIdx.z, c0 = blockIdx.y * 32, n0 = blockIdx.x * 32;
    int tx = threadIdx.x, ty = threadIdx.y;
    const float* xb = x + ((size_t)b * 256 + c0) * 4096 + n0;
#pragma unroll
    for (int j = 0; j < 4; j++) {
        int r = ty + 8 * j;
        tile[r][tx] = xb[(size_t)r * 4096 + tx];
    }
    __syncthreads();
    int c = c0 + tx;
    int g = c >> 5;
    float mu = stats[(b * 8 + g) * 2], rs = stats[(b * 8 + g) * 2 + 1];
    float sc = rs * gw[c];
    float sh = gb[c] - mu * sc;
    u16* o = xnT + ((size_t)b * 4096 + n0) * 256 + c;
#pragma unroll
    for (int j = 0; j < 4; j++) {
        int r = ty + 8 * j;
        float v = tile[tx][r];
        o[(size_t)r * 256] = f2bf(v * sc + sh);
    }
}

// ---------------- Kernel 4: QKV GEMM (M=768,K=256,N=4096 per batch) ---------
// A = wq (row-major, K contiguous), B = xnT[b][n][c] (K=c contiguous)
// epilogue: +bias; q scaled 0.125 -> qT[bh][n][64]; k -> kT[bh][n][64]; v -> vv[bh][64][n]
__global__ void __launch_bounds__(256) qkv_gemm_k(const u16* __restrict__ wq,
                                                  const float* __restrict__ qkvb,
                                                  const u16* __restrict__ xnT,
                                                  u16* __restrict__ qT,
                                                  u16* __restrict__ kT,
                                                  u16* __restrict__ vv) {
    int b  = blockIdx.z;
    int w  = threadIdx.x >> 6, l = threadIdx.x & 63;
    int lr = l & 15, lg = l >> 4;
    int m0 = blockIdx.y * 64 + w * 16;
    int n0 = blockIdx.x * 64;
    f32x4 acc[4];
#pragma unroll
    for (int g = 0; g < 4; g++) acc[g] = (f32x4){0.f, 0.f, 0.f, 0.f};
    const u16* ap = wq + (size_t)(m0 + lr) * 256 + 8 * lg;
    const u16* bp = xnT + ((size_t)b * 4096 + n0 + lr) * 256 + 8 * lg;
#pragma unroll 2
    for (int k0 = 0; k0 < 256; k0 += 32) {
        bf16x8 a = *reinterpret_cast<const bf16x8*>(ap + k0);
#pragma unroll
        for (int g = 0; g < 4; g++) {
            bf16x8 bb = *reinterpret_cast<const bf16x8*>(bp + (size_t)g * 16 * 256 + k0);
            acc[g] = __builtin_amdgcn_mfma_f32_16x16x32_bf16(a, bb, acc[g], 0, 0, 0);
        }
    }
#pragma unroll
    for (int g = 0; g < 4; g++) {
#pragma unroll
        for (int j = 0; j < 4; j++) {
            int o = m0 + lg * 4 + j;
            int n = n0 + g * 16 + lr;
            float v = acc[g][j] + qkvb[o];
            int sec = o >> 8;
            int oc  = o & 255;
            int h = oc >> 6, ch = oc & 63;
            size_t bh = (size_t)(b * 4 + h);
            if (sec == 0)      qT[(bh * 4096 + n) * 64 + ch] = f2bf(v * 0.125f);
            else if (sec == 1) kT[(bh * 4096 + n) * 64 + ch] = f2bf(v);
            else               vv[(bh * 64 + ch) * 4096 + n] = f2bf(v);
        }
    }
}

// ---------------- Kernel 5: flash attention -------------------------------
// per (b,h): Q,K as [n][64] (K-contig), V as [64][n] (m-contig)
// block = 4 waves, each wave owns 16 query rows; m-tiles of 64
__global__ void __launch_bounds__(256) attn_k(const u16* __restrict__ qT,
                                              const u16* __restrict__ kT,
                                              const u16* __restrict__ vv,
                                              u16* __restrict__ oT) {
    __shared__ u16 p_lds[4][16][72];  // per-wave P tile, padded (+8) rows
    int bh = blockIdx.y;
    int b = bh >> 2, h = bh & 3;
    int w = threadIdx.x >> 6, l = threadIdx.x & 63;
    int lr = l & 15, lg = l >> 4;
    int nr0 = blockIdx.x * 64 + w * 16;
    const u16* qp = qT + (size_t)bh * 4096 * 64;
    const u16* kp = kT + (size_t)bh * 4096 * 64;
    const u16* vp = vv + (size_t)bh * 64 * 4096;

    bf16x8 qa[2];
    qa[0] = *reinterpret_cast<const bf16x8*>(qp + (size_t)(nr0 + lr) * 64 + 8 * lg);
    qa[1] = *reinterpret_cast<const bf16x8*>(qp + (size_t)(nr0 + lr) * 64 + 32 + 8 * lg);

    f32x4 oacc[4];
#pragma unroll
    for (int g = 0; g < 4; g++) oacc[g] = (f32x4){0.f, 0.f, 0.f, 0.f};
    float mrow[4] = {-__builtin_inff(), -__builtin_inff(), -__builtin_inff(), -__builtin_inff()};
    float lrow[4] = {0.f, 0.f, 0.f, 0.f};

    for (int m0 = 0; m0 < 4096; m0 += 64) {
        f32x4 s[4];
#pragma unroll
        for (int g = 0; g < 4; g++) s[g] = (f32x4){0.f, 0.f, 0.f, 0.f};
#pragma unroll
        for (int g = 0; g < 4; g++) {
            const u16* kb = kp + (size_t)(m0 + g * 16 + lr) * 64 + 8 * lg;
            s[g] = __builtin_amdgcn_mfma_f32_16x16x32_bf16(
                qa[0], *reinterpret_cast<const bf16x8*>(kb), s[g], 0, 0, 0);
            s[g] = __builtin_amdgcn_mfma_f32_16x16x32_bf16(
                qa[1], *reinterpret_cast<const bf16x8*>(kb + 32), s[g], 0, 0, 0);
        }
        // online softmax (rows live across the 16 lanes of each l>>4 group)
        float alpha[4];
#pragma unroll
        for (int j = 0; j < 4; j++) {
            float m = fmaxf(fmaxf(s[0][j], s[1][j]), fmaxf(s[2][j], s[3][j]));
            m = fmaxf(m, __shfl_xor(m, 1, 64));
            m = fmaxf(m, __shfl_xor(m, 2, 64));
            m = fmaxf(m, __shfl_xor(m, 4, 64));
            m = fmaxf(m, __shfl_xor(m, 8, 64));
            float mn = fmaxf(mrow[j], m);
            alpha[j] = __expf(mrow[j] - mn);
            mrow[j] = mn;
            float rs = 0.f;
#pragma unroll
            for (int g = 0; g < 4; g++) {
                float p = __expf(s[g][j] - mn);
                s[g][j] = p;
                rs += p;
            }
            rs += __shfl_xor(rs, 1, 64);
            rs += __shfl_xor(rs, 2, 64);
            rs += __shfl_xor(rs, 4, 64);
            rs += __shfl_xor(rs, 8, 64);
            lrow[j] = lrow[j] * alpha[j] + rs;
        }
#pragma unroll
        for (int g = 0; g < 4; g++)
#pragma unroll
            for (int j = 0; j < 4; j++) oacc[g][j] *= alpha[j];
        // P -> LDS (bf16), re-layout for A-fragments
#pragma unroll
        for (int g = 0; g < 4; g++)
#pragma unroll
            for (int j = 0; j < 4; j++)
                p_lds[w][lg * 4 + j][g * 16 + lr] = f2bf(s[g][j]);
        __syncthreads();
#pragma unroll
        for (int ks = 0; ks < 2; ks++) {
            bf16x8 pa = *reinterpret_cast<const bf16x8*>(&p_lds[w][lr][ks * 32 + 8 * lg]);
#pragma unroll
            for (int cg = 0; cg < 4; cg++) {
                bf16x8 vb = *reinterpret_cast<const bf16x8*>(
                    vp + (size_t)(cg * 16 + lr) * 4096 + m0 + ks * 32 + 8 * lg);
                oacc[cg] = __builtin_amdgcn_mfma_f32_16x16x32_bf16(pa, vb, oacc[cg], 0, 0, 0);
            }
        }
        __syncthreads();
    }
    // epilogue: O[n][c] / l -> oT[b][n][h*64+c] bf16
#pragma unroll
    for (int cg = 0; cg < 4; cg++)
#pragma unroll
        for (int j = 0; j < 4; j++) {
            int n = nr0 + lg * 4 + j;
            float v = oacc[cg][j] / lrow[j];
            oT[((size_t)b * 4096 + n) * 256 + h * 64 + cg * 16 + lr] = f2bf(v);
        }
}

// ---------------- Kernel 6: proj GEMM + bias + residual --------------------
__global__ void __launch_bounds__(256) proj_gemm_k(const u16* __restrict__ wp,
                                                   const float* __restrict__ pb,
                                                   const u16* __restrict__ oT,
                                                   const float* __restrict__ x,
                                                   float* __restrict__ out) {
    int b  = blockIdx.z;
    int w  = threadIdx.x >> 6, l = threadIdx.x & 63;
    int lr = l & 15, lg = l >> 4;
    int m0 = blockIdx.y * 64 + w * 16;
    int n0 = blockIdx.x * 64;
    f32x4 acc[4];
#pragma unroll
    for (int g = 0; g < 4; g++) acc[g] = (f32x4){0.f, 0.f, 0.f, 0.f};
    const u16* ap = wp + (size_t)(m0 + lr) * 256 + 8 * lg;
    const u16* bp = oT + ((size_t)b * 4096 + n0 + lr) * 256 + 8 * lg;
#pragma unroll 2
    for (int k0 = 0; k0 < 256; k0 += 32) {
        bf16x8 a = *reinterpret_cast<const bf16x8*>(ap + k0);
#pragma unroll
        for (int g = 0; g < 4; g++) {
            bf16x8 bb = *reinterpret_cast<const bf16x8*>(bp + (size_t)g * 16 * 256 + k0);
            acc[g] = __builtin_amdgcn_mfma_f32_16x16x32_bf16(a, bb, acc[g], 0, 0, 0);
        }
    }
#pragma unroll
    for (int g = 0; g < 4; g++)
#pragma unroll
        for (int j = 0; j < 4; j++) {
            int o = m0 + lg * 4 + j;
            int n = n0 + g * 16 + lr;
            size_t idx = ((size_t)b * 256 + o) * 4096 + n;
            out[idx] = x[idx] + pb[o] + acc[g][j];
        }
}

// ---------------------------------------------------------------------------
extern "C" void kernel_launch(void* const* d_in, const int* in_sizes, int n_in,
                              void* d_out, int out_size, void* d_ws, size_t ws_size,
                              hipStream_t stream) {
    const float* x      = (const float*)d_in[0];
    const float* gn_w   = (const float*)d_in[1];
    const float* gn_b   = (const float*)d_in[2];
    const float* qkv_w  = (const float*)d_in[3];
    const float* qkv_b  = (const float*)d_in[4];
    const float* proj_w = (const float*)d_in[5];
    const float* proj_b = (const float*)d_in[6];
    float* out = (float*)d_out;

    char* ws = (char*)d_ws;
    float* stats = (float*)(ws + 0);            //      256 B
    u16* wq  = (u16*)(ws + 256);                //  393216 B
    u16* wp  = (u16*)(ws + 393472);             //  131072 B
    u16* xnT = (u16*)(ws + 524544);             // 8388608 B  [b][n][256]
    u16* qT  = (u16*)(ws + 8913152);            // 8388608 B  [bh][n][64]
    u16* kT  = (u16*)(ws + 17301760);           // 8388608 B  [bh][n][64]
    u16* vv  = (u16*)(ws + 25690368);           // 8388608 B  [bh][64][n]
    u16* oT  = (u16*)(ws + 34078976);           // 8388608 B  [b][n][256]

    gn_stats_k<<<dim3(32), dim3(256), 0, stream>>>(x, stats);
    convw_k<<<dim3(768), dim3(256), 0, stream>>>(qkv_w, proj_w, wq, wp);
    gnorm_t_k<<<dim3(128, 8, 4), dim3(32, 8), 0, stream>>>(x, stats, gn_w, gn_b, xnT);
    qkv_gemm_k<<<dim3(64, 12, 4), dim3(256), 0, stream>>>(wq, qkv_b, xnT, qT, kT, vv);
    attn_k<<<dim3(64, 16), dim3(256), 0, stream>>>(qT, kT, vv, oT);
    proj_gemm_k<<<dim3(64, 4, 4), dim3(256), 0, stream>>>(wp, proj_b, oT, x, out);
}

// Round 3
// 315.546 us; speedup vs baseline: 2.4505x; 2.4505x over previous
//
#include <hip/hip_runtime.h>
#include <hip/hip_bf16.h>

typedef unsigned short u16;
typedef __attribute__((ext_vector_type(4))) float f32x4;
typedef __attribute__((ext_vector_type(16))) float f32x16;
typedef __attribute__((ext_vector_type(8))) __bf16 bf16x8;
typedef __attribute__((ext_vector_type(2))) unsigned u32x2;

#define DEVI static __device__ __forceinline__
#define MFMA32 __builtin_amdgcn_mfma_f32_32x32x16_bf16

#if defined(__has_builtin)
#if __has_builtin(__builtin_amdgcn_exp2f)
#define HAVE_EXP2 1
#endif
#endif

#ifdef HAVE_EXP2
#define EXPX(x) __builtin_amdgcn_exp2f(x)
#define QSCALE 0.18033688011112042f /* 0.125 * log2(e): softmax in exp2 domain */
#define THRX 11.5f
#else
#define EXPX(x) __expf(x)
#define QSCALE 0.125f
#define THRX 8.0f
#endif

DEVI u16 f2bf(float f) {
    union { float f; unsigned u; } v; v.f = f;
    unsigned r = v.u + 0x7fffu + ((v.u >> 16) & 1u);
    return (u16)(r >> 16);
}

DEVI unsigned cvtpk(float lo, float hi_) {
    unsigned r;
    asm("v_cvt_pk_bf16_f32 %0, %1, %2" : "=v"(r) : "v"(lo), "v"(hi_));
    return r;
}

// permlane32_swap: o0 = {a.lo | b.lo-from-partner}, o1 = {a.hi-from-partner | b.hi}
// lane<32: o0=own a, o1=partner a ; lane>=32: o0=partner b, o1=own b
DEVI void plswap(unsigned a, unsigned b, unsigned& o0, unsigned& o1) {
#if defined(__has_builtin) && __has_builtin(__builtin_amdgcn_permlane32_swap)
    u32x2 r = __builtin_amdgcn_permlane32_swap(a, b, false, false);
    o0 = r[0]; o1 = r[1];
#else
    unsigned xa = (unsigned)__shfl_xor((int)a, 32, 64);
    unsigned xb = (unsigned)__shfl_xor((int)b, 32, 64);
    bool hi = (threadIdx.x & 32) != 0;
    o0 = hi ? xb : a;
    o1 = hi ? b : xa;
#endif
}

// ---------------- Kernel 1: GroupNorm stats (mean, rstd per (b,g)) ----------
__global__ void __launch_bounds__(256) gn_stats_k(const float* __restrict__ x,
                                                  float* __restrict__ stats) {
    int bg = blockIdx.x;  // group = 32 ch * 4096 = 131072 elems
    const float4* p = reinterpret_cast<const float4*>(x + (size_t)bg * 131072);
    float s = 0.f, s2 = 0.f;
    for (int i = threadIdx.x; i < 32768; i += 256) {
        float4 v = p[i];
        s  += v.x + v.y + v.z + v.w;
        s2 += v.x * v.x + v.y * v.y + v.z * v.z + v.w * v.w;
    }
    for (int off = 32; off; off >>= 1) {
        s  += __shfl_down(s,  off, 64);
        s2 += __shfl_down(s2, off, 64);
    }
    __shared__ float sb[8];
    int w = threadIdx.x >> 6, l = threadIdx.x & 63;
    if (l == 0) { sb[w] = s; sb[4 + w] = s2; }
    __syncthreads();
    if (threadIdx.x == 0) {
        float ts  = sb[0] + sb[1] + sb[2] + sb[3];
        float ts2 = sb[4] + sb[5] + sb[6] + sb[7];
        float mu  = ts * (1.f / 131072.f);
        float var = ts2 * (1.f / 131072.f) - mu * mu;
        stats[bg * 2]     = mu;
        stats[bg * 2 + 1] = rsqrtf(var + 1e-5f);
    }
}

// ---------------- Kernel 2: weights fp32 -> bf16 ----------------------------
__global__ void __launch_bounds__(256) convw_k(const float* __restrict__ qw,
                                               const float* __restrict__ pw,
                                               u16* __restrict__ wq,
                                               u16* __restrict__ wp) {
    int i = blockIdx.x * 256 + threadIdx.x;
    if (i < 196608) wq[i] = f2bf(qw[i]);
    if (i < 65536)  wp[i] = f2bf(pw[i]);
}

// ---------------- Kernel 3: normalize + transpose -> xnT[b][n][c] bf16 ------
__global__ void __launch_bounds__(256) gnorm_t_k(const float* __restrict__ x,
                                                 const float* __restrict__ stats,
                                                 const float* __restrict__ gw,
                                                 const float* __restrict__ gb,
                                                 u16* __restrict__ xnT) {
    __shared__ float tile[32][33];
    int b = blockIdx.z, c0 = blockIdx.y * 32, n0 = blockIdx.x * 32;
    int tx = threadIdx.x, ty = threadIdx.y;
    const float* xb = x + ((size_t)b * 256 + c0) * 4096 + n0;
#pragma unroll
    for (int j = 0; j < 4; j++) {
        int r = ty + 8 * j;
        tile[r][tx] = xb[(size_t)r * 4096 + tx];
    }
    __syncthreads();
    int c = c0 + tx;
    int g = c >> 5;
    float mu = stats[(b * 8 + g) * 2], rs = stats[(b * 8 + g) * 2 + 1];
    float sc = rs * gw[c];
    float sh = gb[c] - mu * sc;
    u16* o = xnT + ((size_t)b * 4096 + n0) * 256 + c;
#pragma unroll
    for (int j = 0; j < 4; j++) {
        int r = ty + 8 * j;
        float v = tile[tx][r];
        o[(size_t)r * 256] = f2bf(v * sc + sh);
    }
}

// ---------------- Kernel 4: QKV GEMM (M=768,K=256,N=4096 per batch) ---------
__global__ void __launch_bounds__(256) qkv_gemm_k(const u16* __restrict__ wq,
                                                  const float* __restrict__ qkvb,
                                                  const u16* __restrict__ xnT,
                                                  u16* __restrict__ qT,
                                                  u16* __restrict__ kT,
                                                  u16* __restrict__ vv) {
    int b  = blockIdx.z;
    int w  = threadIdx.x >> 6, l = threadIdx.x & 63;
    int lr = l & 15, lg = l >> 4;
    int m0 = blockIdx.y * 64 + w * 16;
    int n0 = blockIdx.x * 64;
    f32x4 acc[4];
#pragma unroll
    for (int g = 0; g < 4; g++) acc[g] = (f32x4){0.f, 0.f, 0.f, 0.f};
    const u16* ap = wq + (size_t)(m0 + lr) * 256 + 8 * lg;
    const u16* bp = xnT + ((size_t)b * 4096 + n0 + lr) * 256 + 8 * lg;
#pragma unroll 2
    for (int k0 = 0; k0 < 256; k0 += 32) {
        bf16x8 a = *reinterpret_cast<const bf16x8*>(ap + k0);
#pragma unroll
        for (int g = 0; g < 4; g++) {
            bf16x8 bb = *reinterpret_cast<const bf16x8*>(bp + (size_t)g * 16 * 256 + k0);
            acc[g] = __builtin_amdgcn_mfma_f32_16x16x32_bf16(a, bb, acc[g], 0, 0, 0);
        }
    }
#pragma unroll
    for (int g = 0; g < 4; g++) {
#pragma unroll
        for (int j = 0; j < 4; j++) {
            int o = m0 + lg * 4 + j;
            int n = n0 + g * 16 + lr;
            float v = acc[g][j] + qkvb[o];
            int sec = o >> 8;
            int oc  = o & 255;
            int h = oc >> 6, ch = oc & 63;
            size_t bh = (size_t)(b * 4 + h);
            if (sec == 0)      qT[(bh * 4096 + n) * 64 + ch] = f2bf(v * QSCALE);
            else if (sec == 1) kT[(bh * 4096 + n) * 64 + ch] = f2bf(v);
            else               vv[(bh * 64 + ch) * 4096 + n] = f2bf(v);
        }
    }
}

// ---------------- Kernel 5: flash attention, 32x32 swapped-QK ---------------
// Block = 4 waves x 32 q-rows = 128 rows. KVBLK=32, K/V double-buffered in LDS.
// S^T = mfma(K, Q): lane holds S[q = lane&31][16 keys via reg pattern].
// Softmax fully in-register; P->A-frags via cvt_pk_bf16 + permlane32_swap.
__global__ void __launch_bounds__(256) attn_k(const u16* __restrict__ qT,
                                              const u16* __restrict__ kT,
                                              const u16* __restrict__ vv,
                                              u16* __restrict__ oT) {
    __shared__ __align__(16) u16 kbuf[2][2048];  // [key 0..31][d 0..63], XOR-swz
    __shared__ __align__(16) u16 vbuf[2][2048];  // [d 0..63][key 0..31], XOR-swz
    const int bh = blockIdx.y, b = bh >> 2, h = bh & 3;
    const int tid = threadIdx.x;
    const int w = tid >> 6, l = tid & 63;
    const int q5 = l & 31, hi = l >> 5;
    const int n0w = blockIdx.x * 128 + w * 32;
    const u16* qp = qT + (size_t)bh * 262144;
    const u16* kp = kT + (size_t)bh * 262144;
    const u16* vp = vv + (size_t)bh * 262144;

    // Q fragments (B-operand: col = q5, k-halves by hi)
    const u16* qrow = qp + (size_t)(n0w + q5) * 64 + 8 * hi;
    const bf16x8 qf0 = *(const bf16x8*)(qrow);
    const bf16x8 qf1 = *(const bf16x8*)(qrow + 16);
    const bf16x8 qf2 = *(const bf16x8*)(qrow + 32);
    const bf16x8 qf3 = *(const bf16x8*)(qrow + 48);

    // staging: wave w stages 1KB of K (8 rows) and 1KB of V (16 d-rows)
    const int krow = 8 * w + (l >> 3);
    const int kw_lds = krow * 64 + (((l & 7) ^ (l >> 3)) << 3);
    const u16* kg = kp + (size_t)krow * 64 + (l & 7) * 8;
    const int vd = 16 * w + (l >> 2);
    const int vw_lds = vd * 32 + (((l & 3) ^ ((l >> 2) & 3)) << 3);
    const u16* vg = vp + (size_t)vd * 4096 + (l & 3) * 8;

    const int ksw = (q5 & 7) << 3;   // K-read swizzle (u16 units)
    const int vsw = (q5 & 3) << 3;   // V-read swizzle

    f32x16 o0, o1;
#pragma unroll
    for (int r = 0; r < 16; ++r) { o0[r] = 0.f; o1[r] = 0.f; }
    float mrun = -3.0e38f, lsum = 0.f;

    {   // prologue: stage tile 0
        bf16x8 k0 = *(const bf16x8*)(kg);
        bf16x8 v0 = *(const bf16x8*)(vg);
        *(bf16x8*)&kbuf[0][kw_lds] = k0;
        *(bf16x8*)&vbuf[0][vw_lds] = v0;
    }
    __syncthreads();

    int cur = 0;
    for (int it = 0; it < 128; ++it) {
        bf16x8 knx, vnx;
        const bool pre = (it < 127);
        if (pre) {  // issue next-tile global loads early; latency hides under compute
            knx = *(const bf16x8*)(kg + (size_t)(it + 1) * 2048);
            vnx = *(const bf16x8*)(vg + (it + 1) * 32);
        }
        // ---- QK^T: s[r] = S[q5][key=(r&3)+8*(r>>2)+4*hi] (exp2 domain) ----
        f32x16 s;
#pragma unroll
        for (int r = 0; r < 16; ++r) s[r] = 0.f;
        {
            const u16* kb = &kbuf[cur][q5 * 64];
            s = MFMA32(*(const bf16x8*)(kb + ((8 * hi) ^ ksw)),      qf0, s, 0, 0, 0);
            s = MFMA32(*(const bf16x8*)(kb + ((16 + 8 * hi) ^ ksw)), qf1, s, 0, 0, 0);
            s = MFMA32(*(const bf16x8*)(kb + ((32 + 8 * hi) ^ ksw)), qf2, s, 0, 0, 0);
            s = MFMA32(*(const bf16x8*)(kb + ((48 + 8 * hi) ^ ksw)), qf3, s, 0, 0, 0);
        }
        // ---- online softmax, in-register ----
        float pm = s[0];
#pragma unroll
        for (int r = 1; r < 16; ++r) pm = fmaxf(pm, s[r]);
        pm = fmaxf(pm, __shfl_xor(pm, 32, 64));
        if (!__all(pm - mrun <= THRX)) {  // defer-rescale (T13)
            float mnew = fmaxf(mrun, pm);
            float al = EXPX(mrun - mnew);
            mrun = mnew;
            lsum *= al;
#pragma unroll
            for (int r = 0; r < 16; ++r) {
                float ar = __shfl(al, (r & 3) + 8 * (r >> 2) + 4 * hi, 64);
                o0[r] *= ar; o1[r] *= ar;
            }
        }
#pragma unroll
        for (int r = 0; r < 16; ++r) s[r] = EXPX(s[r] - mrun);
        float rs = 0.f;
#pragma unroll
        for (int r = 0; r < 16; ++r) rs += s[r];
        rs += __shfl_xor(rs, 32, 64);
        lsum += rs;
        // ---- P -> bf16 A-fragments (T12: cvt_pk + permlane32_swap) ----
        unsigned c0 = cvtpk(s[0], s[1]),   c1 = cvtpk(s[2], s[3]);
        unsigned c2 = cvtpk(s[4], s[5]),   c3 = cvtpk(s[6], s[7]);
        unsigned c4 = cvtpk(s[8], s[9]),   c5 = cvtpk(s[10], s[11]);
        unsigned c6 = cvtpk(s[12], s[13]), c7 = cvtpk(s[14], s[15]);
        unsigned x0a, x0b, y0a, y0b, x1a, x1b, y1a, y1b;
        plswap(c0, c2, x0a, x0b);
        plswap(c1, c3, y0a, y0b);
        plswap(c4, c6, x1a, x1b);
        plswap(c5, c7, y1a, y1b);
        union { unsigned u[4]; bf16x8 v; } pa0, pa1;
        pa0.u[0] = x0a; pa0.u[1] = y0a; pa0.u[2] = x0b; pa0.u[3] = y0b;
        pa1.u[0] = x1a; pa1.u[1] = y1a; pa1.u[2] = x1b; pa1.u[3] = y1b;
        // ---- PV: O[q][d] += P * V ----
        {
            const u16* vb0 = &vbuf[cur][(size_t)q5 * 32];
            const u16* vb1 = &vbuf[cur][(size_t)(32 + q5) * 32];
            bf16x8 v00 = *(const bf16x8*)(vb0 + ((8 * hi) ^ vsw));
            bf16x8 v10 = *(const bf16x8*)(vb0 + ((16 + 8 * hi) ^ vsw));
            bf16x8 v01 = *(const bf16x8*)(vb1 + ((8 * hi) ^ vsw));
            bf16x8 v11 = *(const bf16x8*)(vb1 + ((16 + 8 * hi) ^ vsw));
            o0 = MFMA32(pa0.v, v00, o0, 0, 0, 0);
            o0 = MFMA32(pa1.v, v10, o0, 0, 0, 0);
            o1 = MFMA32(pa0.v, v01, o1, 0, 0, 0);
            o1 = MFMA32(pa1.v, v11, o1, 0, 0, 0);
        }
        if (pre) {  // write next tile into the other buffer
            *(bf16x8*)&kbuf[cur ^ 1][kw_lds] = knx;
            *(bf16x8*)&vbuf[cur ^ 1][vw_lds] = vnx;
        }
        __syncthreads();
        cur ^= 1;
    }
    // ---- epilogue: O[q][d]/lsum -> oT[b][n][h*64+d] ----
    float linv = 1.f / lsum;
    u16* ob = oT + ((size_t)b * 4096 + n0w) * 256 + h * 64 + q5;
#pragma unroll
    for (int r = 0; r < 16; ++r) {
        int qo = (r & 3) + 8 * (r >> 2) + 4 * hi;
        float lr_ = __shfl(linv, qo, 64);
        ob[(size_t)qo * 256]      = f2bf(o0[r] * lr_);
        ob[(size_t)qo * 256 + 32] = f2bf(o1[r] * lr_);
    }
}

// ---------------- Kernel 6: proj GEMM + bias + residual --------------------
__global__ void __launch_bounds__(256) proj_gemm_k(const u16* __restrict__ wp,
                                                   const float* __restrict__ pb,
                                                   const u16* __restrict__ oT,
                                                   const float* __restrict__ x,
                                                   float* __restrict__ out) {
    int b  = blockIdx.z;
    int w  = threadIdx.x >> 6, l = threadIdx.x & 63;
    int lr = l & 15, lg = l >> 4;
    int m0 = blockIdx.y * 64 + w * 16;
    int n0 = blockIdx.x * 64;
    f32x4 acc[4];
#pragma unroll
    for (int g = 0; g < 4; g++) acc[g] = (f32x4){0.f, 0.f, 0.f, 0.f};
    const u16* ap = wp + (size_t)(m0 + lr) * 256 + 8 * lg;
    const u16* bp = oT + ((size_t)b * 4096 + n0 + lr) * 256 + 8 * lg;
#pragma unroll 2
    for (int k0 = 0; k0 < 256; k0 += 32) {
        bf16x8 a = *reinterpret_cast<const bf16x8*>(ap + k0);
#pragma unroll
        for (int g = 0; g < 4; g++) {
            bf16x8 bb = *reinterpret_cast<const bf16x8*>(bp + (size_t)g * 16 * 256 + k0);
            acc[g] = __builtin_amdgcn_mfma_f32_16x16x32_bf16(a, bb, acc[g], 0, 0, 0);
        }
    }
#pragma unroll
    for (int g = 0; g < 4; g++)
#pragma unroll
        for (int j = 0; j < 4; j++) {
            int o = m0 + lg * 4 + j;
            int n = n0 + g * 16 + lr;
            size_t idx = ((size_t)b * 256 + o) * 4096 + n;
            out[idx] = x[idx] + pb[o] + acc[g][j];
        }
}

// ---------------------------------------------------------------------------
extern "C" void kernel_launch(void* const* d_in, const int* in_sizes, int n_in,
                              void* d_out, int out_size, void* d_ws, size_t ws_size,
                              hipStream_t stream) {
    const float* x      = (const float*)d_in[0];
    const float* gn_w   = (const float*)d_in[1];
    const float* gn_b   = (const float*)d_in[2];
    const float* qkv_w  = (const float*)d_in[3];
    const float* qkv_b  = (const float*)d_in[4];
    const float* proj_w = (const float*)d_in[5];
    const float* proj_b = (const float*)d_in[6];
    float* out = (float*)d_out;

    char* ws = (char*)d_ws;
    float* stats = (float*)(ws + 0);            //      256 B
    u16* wq  = (u16*)(ws + 256);                //  393216 B
    u16* wp  = (u16*)(ws + 393472);             //  131072 B
    u16* xnT = (u16*)(ws + 524544);             // 8388608 B  [b][n][256]
    u16* qT  = (u16*)(ws + 8913152);            // 8388608 B  [bh][n][64]
    u16* kT  = (u16*)(ws + 17301760);           // 8388608 B  [bh][n][64]
    u16* vv  = (u16*)(ws + 25690368);           // 8388608 B  [bh][64][n]
    u16* oT  = (u16*)(ws + 34078976);           // 8388608 B  [b][n][256]

    gn_stats_k<<<dim3(32), dim3(256), 0, stream>>>(x, stats);
    convw_k<<<dim3(768), dim3(256), 0, stream>>>(qkv_w, proj_w, wq, wp);
    gnorm_t_k<<<dim3(128, 8, 4), dim3(32, 8), 0, stream>>>(x, stats, gn_w, gn_b, xnT);
    qkv_gemm_k<<<dim3(64, 12, 4), dim3(256), 0, stream>>>(wq, qkv_b, xnT, qT, kT, vv);
    attn_k<<<dim3(32, 16), dim3(256), 0, stream>>>(qT, kT, vv, oT);
    proj_gemm_k<<<dim3(64, 4, 4), dim3(256), 0, stream>>>(wp, proj_b, oT, x, out);
}

// Round 5
// 267.906 us; speedup vs baseline: 2.8863x; 1.1778x over previous
//
#include <hip/hip_runtime.h>
#include <hip/hip_bf16.h>

typedef unsigned short u16;
typedef __attribute__((ext_vector_type(4))) float f32x4;
typedef __attribute__((ext_vector_type(16))) float f32x16;
typedef __attribute__((ext_vector_type(8))) __bf16 bf16x8;
typedef __attribute__((ext_vector_type(2))) unsigned u32x2;

#define DEVI static __device__ __forceinline__
#define MFMA32 __builtin_amdgcn_mfma_f32_32x32x16_bf16

#if defined(__has_builtin)
#if __has_builtin(__builtin_amdgcn_exp2f)
#define HAVE_EXP2 1
#endif
#endif

#ifdef HAVE_EXP2
#define EXPX(x) __builtin_amdgcn_exp2f(x)
#define QSCALE 0.18033688011112042f /* 0.125 * log2(e): softmax in exp2 domain */
#define THRX 11.5f
#else
#define EXPX(x) __expf(x)
#define QSCALE 0.125f
#define THRX 8.0f
#endif

DEVI u16 f2bf(float f) {
    union { float f; unsigned u; } v; v.f = f;
    unsigned r = v.u + 0x7fffu + ((v.u >> 16) & 1u);
    return (u16)(r >> 16);
}

DEVI unsigned cvtpk(float lo, float hi_) {
    unsigned r;
    asm("v_cvt_pk_bf16_f32 %0, %1, %2" : "=v"(r) : "v"(lo), "v"(hi_));
    return r;
}

DEVI void plswap(unsigned a, unsigned b, unsigned& o0, unsigned& o1) {
#if defined(__has_builtin) && __has_builtin(__builtin_amdgcn_permlane32_swap)
    u32x2 r = __builtin_amdgcn_permlane32_swap(a, b, false, false);
    o0 = r[0]; o1 = r[1];
#else
    unsigned xa = (unsigned)__shfl_xor((int)a, 32, 64);
    unsigned xb = (unsigned)__shfl_xor((int)b, 32, 64);
    bool hi = (threadIdx.x & 32) != 0;
    o0 = hi ? xb : a;
    o1 = hi ? b : xa;
#endif
}

// async global->LDS, 16B per lane, LDS dest = uniform base + lane*16
DEVI void gld16(const u16* g, u16* l) {
    __builtin_amdgcn_global_load_lds(
        (const __attribute__((address_space(1))) unsigned int*)g,
        (__attribute__((address_space(3))) unsigned int*)l, 16, 0, 0);
}

// ---------------- Kernel 1a: GroupNorm partial sums (256 blocks) ------------
__global__ void __launch_bounds__(256) gn_stats1_k(const float* __restrict__ x,
                                                   float* __restrict__ part) {
    int bid = blockIdx.x;            // 32 bg x 8 segments
    int bg = bid >> 3, seg = bid & 7;
    const float4* p = reinterpret_cast<const float4*>(x + (size_t)bg * 131072 + seg * 16384);
    float s = 0.f, s2 = 0.f;
    for (int i = threadIdx.x; i < 4096; i += 256) {
        float4 v = p[i];
        s  += v.x + v.y + v.z + v.w;
        s2 += v.x * v.x + v.y * v.y + v.z * v.z + v.w * v.w;
    }
    for (int off = 32; off; off >>= 1) {
        s  += __shfl_down(s,  off, 64);
        s2 += __shfl_down(s2, off, 64);
    }
    __shared__ float sb[8];
    int w = threadIdx.x >> 6, l = threadIdx.x & 63;
    if (l == 0) { sb[w] = s; sb[4 + w] = s2; }
    __syncthreads();
    if (threadIdx.x == 0) {
        part[bid * 2]     = sb[0] + sb[1] + sb[2] + sb[3];
        part[bid * 2 + 1] = sb[4] + sb[5] + sb[6] + sb[7];
    }
}

// ---------------- Kernel 1b: finalize stats ---------------------------------
__global__ void gn_stats2_k(const float* __restrict__ part, float* __restrict__ stats) {
    int t = threadIdx.x;
    if (t < 32) {
        float s = 0.f, s2 = 0.f;
#pragma unroll
        for (int i = 0; i < 8; i++) { s += part[(t * 8 + i) * 2]; s2 += part[(t * 8 + i) * 2 + 1]; }
        float mu  = s * (1.f / 131072.f);
        float var = s2 * (1.f / 131072.f) - mu * mu;
        stats[t * 2]     = mu;
        stats[t * 2 + 1] = rsqrtf(var + 1e-5f);
    }
}

// ---------------- Kernel 2: weights fp32 -> bf16 ----------------------------
__global__ void __launch_bounds__(256) convw_k(const float* __restrict__ qw,
                                               const float* __restrict__ pw,
                                               u16* __restrict__ wq,
                                               u16* __restrict__ wp) {
    int i = blockIdx.x * 256 + threadIdx.x;
    if (i < 196608) wq[i] = f2bf(qw[i]);
    if (i < 65536)  wp[i] = f2bf(pw[i]);
}

// ---------------- Kernel 3: normalize + transpose -> xnT[b][n][c] bf16 ------
__global__ void __launch_bounds__(256) gnorm_t_k(const float* __restrict__ x,
                                                 const float* __restrict__ stats,
                                                 const float* __restrict__ gw,
                                                 const float* __restrict__ gb,
                                                 u16* __restrict__ xnT) {
    __shared__ float tile[32][33];
    int b = blockIdx.z, c0 = blockIdx.y * 32, n0 = blockIdx.x * 32;
    int tx = threadIdx.x, ty = threadIdx.y;
    const float* xb = x + ((size_t)b * 256 + c0) * 4096 + n0;
#pragma unroll
    for (int j = 0; j < 4; j++) {
        int r = ty + 8 * j;
        tile[r][tx] = xb[(size_t)r * 4096 + tx];
    }
    __syncthreads();
    int c = c0 + tx;
    int g = c >> 5;
    float mu = stats[(b * 8 + g) * 2], rs = stats[(b * 8 + g) * 2 + 1];
    float sc = rs * gw[c];
    float sh = gb[c] - mu * sc;
    u16* o = xnT + ((size_t)b * 4096 + n0) * 256 + c;
#pragma unroll
    for (int j = 0; j < 4; j++) {
        int r = ty + 8 * j;
        float v = tile[tx][r];
        o[(size_t)r * 256] = f2bf(v * sc + sh);
    }
}

// ---------------- Kernel 4: QKV GEMM + transpose epilogue -------------------
// A = wq row-major K-contig; B = xnT[b][n][256] K-contig.
// Each 64-o block is one section(q/k/v) and one head. Epilogue goes through a
// 64x72 u16 LDS tile so ALL global writes are 16B/lane coalesced.
__global__ void __launch_bounds__(256) qkv_gemm_k(const u16* __restrict__ wq,
                                                  const float* __restrict__ qkvb,
                                                  const u16* __restrict__ xnT,
                                                  u16* __restrict__ qT,
                                                  u16* __restrict__ kT,
                                                  u16* __restrict__ vv) {
    __shared__ __align__(16) u16 T[64 * 72];
    int b  = blockIdx.z;
    int w  = threadIdx.x >> 6, l = threadIdx.x & 63;
    int lr = l & 15, lg = l >> 4;
    int m0b = blockIdx.y * 64;
    int m0 = m0b + w * 16;
    int n0 = blockIdx.x * 64;
    f32x4 acc[4];
#pragma unroll
    for (int g = 0; g < 4; g++) acc[g] = (f32x4){0.f, 0.f, 0.f, 0.f};
    const u16* ap = wq + (size_t)(m0 + lr) * 256 + 8 * lg;
    const u16* bp = xnT + ((size_t)b * 4096 + n0 + lr) * 256 + 8 * lg;
#pragma unroll 2
    for (int k0 = 0; k0 < 256; k0 += 32) {
        bf16x8 a = *reinterpret_cast<const bf16x8*>(ap + k0);
#pragma unroll
        for (int g = 0; g < 4; g++) {
            bf16x8 bb = *reinterpret_cast<const bf16x8*>(bp + (size_t)g * 16 * 256 + k0);
            acc[g] = __builtin_amdgcn_mfma_f32_16x16x32_bf16(a, bb, acc[g], 0, 0, 0);
        }
    }
    int sec  = m0b >> 8;            // 0=q 1=k 2=v
    int hsec = (m0b >> 6) & 3;      // head within section
    float qs = (sec == 0) ? QSCALE : 1.f;
#pragma unroll
    for (int g = 0; g < 4; g++) {
        ushort4 pk;
#pragma unroll
        for (int j = 0; j < 4; j++) {
            int o = m0 + lg * 4 + j;
            float v = (acc[g][j] + qkvb[o]) * qs;
            ((u16*)&pk)[j] = f2bf(v);
        }
        if (sec < 2) {   // tile[n][o_local]
            *(ushort4*)&T[(g * 16 + lr) * 72 + w * 16 + lg * 4] = pk;
        } else {         // tile[o_local][n]
#pragma unroll
            for (int j = 0; j < 4; j++)
                T[(w * 16 + lg * 4 + j) * 72 + g * 16 + lr] = ((u16*)&pk)[j];
        }
    }
    __syncthreads();
    int row = threadIdx.x >> 2;
    u16* dst;
    if (sec < 2) {
        u16* base = (sec == 0 ? qT : kT);
        dst = base + ((size_t)(b * 4 + hsec) * 4096 + n0 + row) * 64;
    } else {
        dst = vv + ((size_t)(b * 4 + hsec) * 64 + row) * 4096 + n0;
    }
#pragma unroll
    for (int p = 0; p < 2; p++) {
        int c = (threadIdx.x & 3) + 4 * p;
        *(ulonglong2*)(dst + c * 8) = *(const ulonglong2*)&T[row * 72 + c * 8];
    }
}

// ---------------- Kernel 5: flash attention, KVBLK=64 -----------------------
// Block = 4 waves x 32 q = 128 rows. K,V tiles 64x64 u16 (128B rows), XOR-swz
// (chunk ^= row&7) applied to the pre-swizzled GLOBAL source; LDS dest linear
// via global_load_lds (16B) -> conflict-free ds_read_b128 by construction.
__global__ void __launch_bounds__(256) attn_k(const u16* __restrict__ qT,
                                              const u16* __restrict__ kT,
                                              const u16* __restrict__ vv,
                                              u16* __restrict__ oT) {
    __shared__ __align__(16) u16 kbuf[2][4096];
    __shared__ __align__(16) u16 vbuf[2][4096];
    const int bh = blockIdx.y, b = bh >> 2, h = bh & 3;
    const int tid = threadIdx.x, w = tid >> 6, l = tid & 63;
    const int q5 = l & 31, hi = l >> 5;
    const int n0w = blockIdx.x * 128 + w * 32;
    const u16* qp = qT + (size_t)bh * 262144;
    const u16* kp = kT + (size_t)bh * 262144;
    const u16* vp = vv + (size_t)bh * 262144;

    // Q fragments (B-operand: col = q5, k-elems 8hi+j, 4 d-steps)
    const u16* qrow = qp + (size_t)(n0w + q5) * 64 + 8 * hi;
    bf16x8 qf[4];
    qf[0] = *(const bf16x8*)(qrow);
    qf[1] = *(const bf16x8*)(qrow + 16);
    qf[2] = *(const bf16x8*)(qrow + 32);
    qf[3] = *(const bf16x8*)(qrow + 48);

    // staging geometry: wave w stages rows 16w..16w+15 (2 issues of 8 rows)
    const int pr = l >> 3, pc = l & 7;
    const int gswz = ((pc ^ pr) << 3);                 // pre-swizzled source chunk
    const u16* kgl = kp + (size_t)(16 * w + pr) * 64 + gswz;
    const u16* vgl = vp + (size_t)(16 * w + pr) * 4096 + gswz;
    const int lbase = 1024 * w;
    const int ksw = q5 & 7;

    f32x16 o0, o1;
#pragma unroll
    for (int r = 0; r < 16; ++r) { o0[r] = 0.f; o1[r] = 0.f; }
    float mrun = -3.0e38f, lsum = 0.f;

#define STAGE(BUF, IT)                                                        \
    {                                                                         \
        const u16* kt_ = kgl + (size_t)(IT) * 4096;                           \
        const u16* vt_ = vgl + (size_t)(IT) * 64;                             \
        gld16(kt_,         &kbuf[BUF][lbase]);                                \
        gld16(kt_ + 512,   &kbuf[BUF][lbase + 512]);                          \
        gld16(vt_,         &vbuf[BUF][lbase]);                                \
        gld16(vt_ + 32768, &vbuf[BUF][lbase + 512]);                          \
    }

    STAGE(0, 0);
    __syncthreads();

    int cur = 0;
    for (int it = 0; it < 64; ++it) {
        if (it < 63) STAGE(cur ^ 1, it + 1);
        const u16* kb = &kbuf[cur][q5 * 64];
        const u16* vb = &vbuf[cur][q5 * 64];
        // ---- QK^T: s0 = S[q5][keys 0..31], s1 = keys 32..63 (exp2 domain) --
        f32x16 s0, s1;
#pragma unroll
        for (int r = 0; r < 16; ++r) { s0[r] = 0.f; s1[r] = 0.f; }
        __builtin_amdgcn_s_setprio(1);
#pragma unroll
        for (int st = 0; st < 4; ++st) {
            int ch = ((hi + 2 * st) ^ ksw) << 3;
            s0 = MFMA32(*(const bf16x8*)(kb + ch),        qf[st], s0, 0, 0, 0);
            s1 = MFMA32(*(const bf16x8*)(kb + 2048 + ch), qf[st], s1, 0, 0, 0);
        }
        __builtin_amdgcn_s_setprio(0);
        // ---- online softmax, in-register ----
        float pm = s0[0];
#pragma unroll
        for (int r = 1; r < 16; ++r) pm = fmaxf(pm, s0[r]);
#pragma unroll
        for (int r = 0; r < 16; ++r) pm = fmaxf(pm, s1[r]);
        pm = fmaxf(pm, __shfl_xor(pm, 32, 64));
        if (!__all(pm - mrun <= THRX)) {   // defer-rescale (T13)
            float mnew = fmaxf(mrun, pm);
            float al = EXPX(mrun - mnew);
            mrun = mnew;
            lsum *= al;
#pragma unroll
            for (int r = 0; r < 16; ++r) {
                float ar = __shfl(al, (r & 3) + 8 * (r >> 2) + 4 * hi, 64);
                o0[r] *= ar; o1[r] *= ar;
            }
        }
        float rs = 0.f;
#pragma unroll
        for (int r = 0; r < 16; ++r) { s0[r] = EXPX(s0[r] - mrun); rs += s0[r]; }
#pragma unroll
        for (int r = 0; r < 16; ++r) { s1[r] = EXPX(s1[r] - mrun); rs += s1[r]; }
        rs += __shfl_xor(rs, 32, 64);
        lsum += rs;
        // ---- P -> bf16 A-fragments (cvt_pk + permlane32_swap) ----
        unsigned c0 = cvtpk(s0[0], s0[1]),   c1 = cvtpk(s0[2], s0[3]);
        unsigned c2 = cvtpk(s0[4], s0[5]),   c3 = cvtpk(s0[6], s0[7]);
        unsigned c4 = cvtpk(s0[8], s0[9]),   c5 = cvtpk(s0[10], s0[11]);
        unsigned c6 = cvtpk(s0[12], s0[13]), c7 = cvtpk(s0[14], s0[15]);
        unsigned d0 = cvtpk(s1[0], s1[1]),   d1 = cvtpk(s1[2], s1[3]);
        unsigned d2 = cvtpk(s1[4], s1[5]),   d3 = cvtpk(s1[6], s1[7]);
        unsigned d4 = cvtpk(s1[8], s1[9]),   d5 = cvtpk(s1[10], s1[11]);
        unsigned d6 = cvtpk(s1[12], s1[13]), d7 = cvtpk(s1[14], s1[15]);
        unsigned x0a, x0b, y0a, y0b, x1a, x1b, y1a, y1b;
        unsigned x2a, x2b, y2a, y2b, x3a, x3b, y3a, y3b;
        plswap(c0, c2, x0a, x0b); plswap(c1, c3, y0a, y0b);
        plswap(c4, c6, x1a, x1b); plswap(c5, c7, y1a, y1b);
        plswap(d0, d2, x2a, x2b); plswap(d1, d3, y2a, y2b);
        plswap(d4, d6, x3a, x3b); plswap(d5, d7, y3a, y3b);
        union { unsigned u[4]; bf16x8 v; } pa0, pa1, pa2, pa3;
        pa0.u[0] = x0a; pa0.u[1] = y0a; pa0.u[2] = x0b; pa0.u[3] = y0b;
        pa1.u[0] = x1a; pa1.u[1] = y1a; pa1.u[2] = x1b; pa1.u[3] = y1b;
        pa2.u[0] = x2a; pa2.u[1] = y2a; pa2.u[2] = x2b; pa2.u[3] = y2b;
        pa3.u[0] = x3a; pa3.u[1] = y3a; pa3.u[2] = x3b; pa3.u[3] = y3b;
        // ---- PV: O[q][d] += P * V ----
        __builtin_amdgcn_s_setprio(1);
        {
            int ch0 = ((0 + hi) ^ ksw) << 3;
            int ch1 = ((2 + hi) ^ ksw) << 3;
            int ch2 = ((4 + hi) ^ ksw) << 3;
            int ch3 = ((6 + hi) ^ ksw) << 3;
            o0 = MFMA32(pa0.v, *(const bf16x8*)(vb + ch0),        o0, 0, 0, 0);
            o1 = MFMA32(pa0.v, *(const bf16x8*)(vb + 2048 + ch0), o1, 0, 0, 0);
            o0 = MFMA32(pa1.v, *(const bf16x8*)(vb + ch1),        o0, 0, 0, 0);
            o1 = MFMA32(pa1.v, *(const bf16x8*)(vb + 2048 + ch1), o1, 0, 0, 0);
            o0 = MFMA32(pa2.v, *(const bf16x8*)(vb + ch2),        o0, 0, 0, 0);
            o1 = MFMA32(pa2.v, *(const bf16x8*)(vb + 2048 + ch2), o1, 0, 0, 0);
            o0 = MFMA32(pa3.v, *(const bf16x8*)(vb + ch3),        o0, 0, 0, 0);
            o1 = MFMA32(pa3.v, *(const bf16x8*)(vb + 2048 + ch3), o1, 0, 0, 0);
        }
        __builtin_amdgcn_s_setprio(0);
        __syncthreads();
        cur ^= 1;
    }
#undef STAGE
    // ---- epilogue: O[q][d]/lsum -> oT[b][n][h*64+d] ----
    float linv = 1.f / lsum;
    u16* ob = oT + ((size_t)b * 4096 + n0w) * 256 + h * 64 + q5;
#pragma unroll
    for (int r = 0; r < 16; ++r) {
        int qo = (r & 3) + 8 * (r >> 2) + 4 * hi;
        float lr_ = __shfl(linv, qo, 64);
        ob[(size_t)qo * 256]      = f2bf(o0[r] * lr_);
        ob[(size_t)qo * 256 + 32] = f2bf(o1[r] * lr_);
    }
}

// ---------------- Kernel 6: proj GEMM + bias + residual --------------------
__global__ void __launch_bounds__(256) proj_gemm_k(const u16* __restrict__ wp,
                                                   const float* __restrict__ pb,
                                                   const u16* __restrict__ oT,
                                                   const float* __restrict__ x,
                                                   float* __restrict__ out) {
    int b  = blockIdx.z;
    int w  = threadIdx.x >> 6, l = threadIdx.x & 63;
    int lr = l & 15, lg = l >> 4;
    int m0 = blockIdx.y * 64 + w * 16;
    int n0 = blockIdx.x * 64;
    f32x4 acc[4];
#pragma unroll
    for (int g = 0; g < 4; g++) acc[g] = (f32x4){0.f, 0.f, 0.f, 0.f};
    const u16* ap = wp + (size_t)(m0 + lr) * 256 + 8 * lg;
    const u16* bp = oT + ((size_t)b * 4096 + n0 + lr) * 256 + 8 * lg;
#pragma unroll 2
    for (int k0 = 0; k0 < 256; k0 += 32) {
        bf16x8 a = *reinterpret_cast<const bf16x8*>(ap + k0);
#pragma unroll
        for (int g = 0; g < 4; g++) {
            bf16x8 bb = *reinterpret_cast<const bf16x8*>(bp + (size_t)g * 16 * 256 + k0);
            acc[g] = __builtin_amdgcn_mfma_f32_16x16x32_bf16(a, bb, acc[g], 0, 0, 0);
        }
    }
#pragma unroll
    for (int g = 0; g < 4; g++)
#pragma unroll
        for (int j = 0; j < 4; j++) {
            int o = m0 + lg * 4 + j;
            int n = n0 + g * 16 + lr;
            size_t idx = ((size_t)b * 256 + o) * 4096 + n;
            out[idx] = x[idx] + pb[o] + acc[g][j];
        }
}

// ---------------------------------------------------------------------------
extern "C" void kernel_launch(void* const* d_in, const int* in_sizes, int n_in,
                              void* d_out, int out_size, void* d_ws, size_t ws_size,
                              hipStream_t stream) {
    const float* x      = (const float*)d_in[0];
    const float* gn_w   = (const float*)d_in[1];
    const float* gn_b   = (const float*)d_in[2];
    const float* qkv_w  = (const float*)d_in[3];
    const float* qkv_b  = (const float*)d_in[4];
    const float* proj_w = (const float*)d_in[5];
    const float* proj_b = (const float*)d_in[6];
    float* out = (float*)d_out;

    char* ws = (char*)d_ws;
    float* stats = (float*)(ws + 0);            //      256 B
    u16* wq  = (u16*)(ws + 256);                //  393216 B
    u16* wp  = (u16*)(ws + 393472);             //  131072 B
    u16* xnT = (u16*)(ws + 524544);             // 8388608 B  [b][n][256]
    u16* qT  = (u16*)(ws + 8913152);            // 8388608 B  [bh][n][64]
    u16* kT  = (u16*)(ws + 17301760);           // 8388608 B  [bh][n][64]
    u16* vv  = (u16*)(ws + 25690368);           // 8388608 B  [bh][64][n]
    u16* oT  = (u16*)(ws + 34078976);           // 8388608 B  [b][n][256]
    float* part = (float*)(ws + 42467584);      //     2048 B

    gn_stats1_k<<<dim3(256), dim3(256), 0, stream>>>(x, part);
    gn_stats2_k<<<dim3(1), dim3(64), 0, stream>>>(part, stats);
    convw_k<<<dim3(768), dim3(256), 0, stream>>>(qkv_w, proj_w, wq, wp);
    gnorm_t_k<<<dim3(128, 8, 4), dim3(32, 8), 0, stream>>>(x, stats, gn_w, gn_b, xnT);
    qkv_gemm_k<<<dim3(64, 12, 4), dim3(256), 0, stream>>>(wq, qkv_b, xnT, qT, kT, vv);
    attn_k<<<dim3(32, 16), dim3(256), 0, stream>>>(qT, kT, vv, oT);
    proj_gemm_k<<<dim3(64, 4, 4), dim3(256), 0, stream>>>(wp, proj_b, oT, x, out);
}

// Round 6
// 266.199 us; speedup vs baseline: 2.9048x; 1.0064x over previous
//
#include <hip/hip_runtime.h>
#include <hip/hip_bf16.h>

typedef unsigned short u16;
typedef __attribute__((ext_vector_type(4))) float f32x4;
typedef __attribute__((ext_vector_type(16))) float f32x16;
typedef __attribute__((ext_vector_type(8))) __bf16 bf16x8;
typedef __attribute__((ext_vector_type(2))) unsigned u32x2;

#define DEVI static __device__ __forceinline__
#define MFMA32 __builtin_amdgcn_mfma_f32_32x32x16_bf16

#if defined(__has_builtin)
#if __has_builtin(__builtin_amdgcn_exp2f)
#define HAVE_EXP2 1
#endif
#endif

#ifdef HAVE_EXP2
#define EXPX(x) __builtin_amdgcn_exp2f(x)
#define QSCALE 0.18033688011112042f /* 0.125 * log2(e): softmax in exp2 domain */
#define THRX 11.5f
#else
#define EXPX(x) __expf(x)
#define QSCALE 0.125f
#define THRX 8.0f
#endif

DEVI u16 f2bf(float f) {
    union { float f; unsigned u; } v; v.f = f;
    unsigned r = v.u + 0x7fffu + ((v.u >> 16) & 1u);
    return (u16)(r >> 16);
}

DEVI float bfu2f(unsigned lo16shifted) {  // takes already-positioned 32b pattern
    union { unsigned u; float f; } v; v.u = lo16shifted; return v.f;
}

DEVI unsigned cvtpk(float lo, float hi_) {
    unsigned r;
    asm("v_cvt_pk_bf16_f32 %0, %1, %2" : "=v"(r) : "v"(lo), "v"(hi_));
    return r;
}

DEVI void plswap(unsigned a, unsigned b, unsigned& o0, unsigned& o1) {
#if defined(__has_builtin) && __has_builtin(__builtin_amdgcn_permlane32_swap)
    u32x2 r = __builtin_amdgcn_permlane32_swap(a, b, false, false);
    o0 = r[0]; o1 = r[1];
#else
    unsigned xa = (unsigned)__shfl_xor((int)a, 32, 64);
    unsigned xb = (unsigned)__shfl_xor((int)b, 32, 64);
    bool hi = (threadIdx.x & 32) != 0;
    o0 = hi ? xb : a;
    o1 = hi ? b : xa;
#endif
}

// async global->LDS, 16B per lane, LDS dest = uniform base + lane*16
DEVI void gld16(const u16* g, u16* l) {
    __builtin_amdgcn_global_load_lds(
        (const __attribute__((address_space(1))) unsigned int*)g,
        (__attribute__((address_space(3))) unsigned int*)l, 16, 0, 0);
}

// ---------------- Kernel 1a: GroupNorm partial sums (256 blocks) ------------
__global__ void __launch_bounds__(256) gn_stats1_k(const float* __restrict__ x,
                                                   float* __restrict__ part) {
    int bid = blockIdx.x;            // 32 bg x 8 segments
    int bg = bid >> 3, seg = bid & 7;
    const float4* p = reinterpret_cast<const float4*>(x + (size_t)bg * 131072 + seg * 16384);
    float s = 0.f, s2 = 0.f;
    for (int i = threadIdx.x; i < 4096; i += 256) {
        float4 v = p[i];
        s  += v.x + v.y + v.z + v.w;
        s2 += v.x * v.x + v.y * v.y + v.z * v.z + v.w * v.w;
    }
    for (int off = 32; off; off >>= 1) {
        s  += __shfl_down(s,  off, 64);
        s2 += __shfl_down(s2, off, 64);
    }
    __shared__ float sb[8];
    int w = threadIdx.x >> 6, l = threadIdx.x & 63;
    if (l == 0) { sb[w] = s; sb[4 + w] = s2; }
    __syncthreads();
    if (threadIdx.x == 0) {
        part[bid * 2]     = sb[0] + sb[1] + sb[2] + sb[3];
        part[bid * 2 + 1] = sb[4] + sb[5] + sb[6] + sb[7];
    }
}

// ---------------- Kernel 1b: finalize stats ---------------------------------
__global__ void gn_stats2_k(const float* __restrict__ part, float* __restrict__ stats) {
    int t = threadIdx.x;
    if (t < 32) {
        float s = 0.f, s2 = 0.f;
#pragma unroll
        for (int i = 0; i < 8; i++) { s += part[(t * 8 + i) * 2]; s2 += part[(t * 8 + i) * 2 + 1]; }
        float mu  = s * (1.f / 131072.f);
        float var = s2 * (1.f / 131072.f) - mu * mu;
        stats[t * 2]     = mu;
        stats[t * 2 + 1] = rsqrtf(var + 1e-5f);
    }
}

// ---------------- Kernel 2: weights fp32 -> bf16 ----------------------------
__global__ void __launch_bounds__(256) convw_k(const float* __restrict__ qw,
                                               const float* __restrict__ pw,
                                               u16* __restrict__ wq,
                                               u16* __restrict__ wp) {
    int i = blockIdx.x * 256 + threadIdx.x;
    if (i < 196608) wq[i] = f2bf(qw[i]);
    if (i < 65536)  wp[i] = f2bf(pw[i]);
}

// ---------------- Kernel 3: normalize + transpose -> xnT[b][n][c] bf16 ------
__global__ void __launch_bounds__(256) gnorm_t_k(const float* __restrict__ x,
                                                 const float* __restrict__ stats,
                                                 const float* __restrict__ gw,
                                                 const float* __restrict__ gb,
                                                 u16* __restrict__ xnT) {
    __shared__ float tile[32][33];
    int b = blockIdx.z, c0 = blockIdx.y * 32, n0 = blockIdx.x * 32;
    int tx = threadIdx.x, ty = threadIdx.y;
    const float* xb = x + ((size_t)b * 256 + c0) * 4096 + n0;
#pragma unroll
    for (int j = 0; j < 4; j++) {
        int r = ty + 8 * j;
        tile[r][tx] = xb[(size_t)r * 4096 + tx];
    }
    __syncthreads();
    int c = c0 + tx;
    int g = c >> 5;
    float mu = stats[(b * 8 + g) * 2], rs = stats[(b * 8 + g) * 2 + 1];
    float sc = rs * gw[c];
    float sh = gb[c] - mu * sc;
    u16* o = xnT + ((size_t)b * 4096 + n0) * 256 + c;
#pragma unroll
    for (int j = 0; j < 4; j++) {
        int r = ty + 8 * j;
        float v = tile[tx][r];
        o[(size_t)r * 256] = f2bf(v * sc + sh);
    }
}

// ---------------- Kernel 4: QKV GEMM + transpose epilogue -------------------
__global__ void __launch_bounds__(256) qkv_gemm_k(const u16* __restrict__ wq,
                                                  const float* __restrict__ qkvb,
                                                  const u16* __restrict__ xnT,
                                                  u16* __restrict__ qT,
                                                  u16* __restrict__ kT,
                                                  u16* __restrict__ vv) {
    __shared__ __align__(16) u16 T[64 * 72];
    int b  = blockIdx.z;
    int w  = threadIdx.x >> 6, l = threadIdx.x & 63;
    int lr = l & 15, lg = l >> 4;
    int m0b = blockIdx.y * 64;
    int m0 = m0b + w * 16;
    int n0 = blockIdx.x * 64;
    f32x4 acc[4];
#pragma unroll
    for (int g = 0; g < 4; g++) acc[g] = (f32x4){0.f, 0.f, 0.f, 0.f};
    const u16* ap = wq + (size_t)(m0 + lr) * 256 + 8 * lg;
    const u16* bp = xnT + ((size_t)b * 4096 + n0 + lr) * 256 + 8 * lg;
#pragma unroll 2
    for (int k0 = 0; k0 < 256; k0 += 32) {
        bf16x8 a = *reinterpret_cast<const bf16x8*>(ap + k0);
#pragma unroll
        for (int g = 0; g < 4; g++) {
            bf16x8 bb = *reinterpret_cast<const bf16x8*>(bp + (size_t)g * 16 * 256 + k0);
            acc[g] = __builtin_amdgcn_mfma_f32_16x16x32_bf16(a, bb, acc[g], 0, 0, 0);
        }
    }
    int sec  = m0b >> 8;            // 0=q 1=k 2=v
    int hsec = (m0b >> 6) & 3;      // head within section
    float qs = (sec == 0) ? QSCALE : 1.f;
#pragma unroll
    for (int g = 0; g < 4; g++) {
        ushort4 pk;
#pragma unroll
        for (int j = 0; j < 4; j++) {
            int o = m0 + lg * 4 + j;
            float v = (acc[g][j] + qkvb[o]) * qs;
            ((u16*)&pk)[j] = f2bf(v);
        }
        if (sec < 2) {   // tile[n][o_local]
            *(ushort4*)&T[(g * 16 + lr) * 72 + w * 16 + lg * 4] = pk;
        } else {         // tile[o_local][n]
#pragma unroll
            for (int j = 0; j < 4; j++)
                T[(w * 16 + lg * 4 + j) * 72 + g * 16 + lr] = ((u16*)&pk)[j];
        }
    }
    __syncthreads();
    int row = threadIdx.x >> 2;
    u16* dst;
    if (sec < 2) {
        u16* base = (sec == 0 ? qT : kT);
        dst = base + ((size_t)(b * 4 + hsec) * 4096 + n0 + row) * 64;
    } else {
        dst = vv + ((size_t)(b * 4 + hsec) * 64 + row) * 4096 + n0;
    }
#pragma unroll
    for (int p = 0; p < 2; p++) {
        int c = (threadIdx.x & 3) + 4 * p;
        *(ulonglong2*)(dst + c * 8) = *(const ulonglong2*)&T[row * 72 + c * 8];
    }
}

// ---------------- Kernel 5: flash attention, split-K x2 ---------------------
// grid (64,16): blockIdx.x = qb128*2 + khalf. Block = 4 waves x 32 q-rows.
// Each block covers keys [khalf*2048, +2048) in 32 iters of KVBLK=64.
// Writes UNNORMALIZED partial O (bf16) + per-row (m,l) f32 for the combine.
__global__ void __launch_bounds__(256, 4) attn_k(const u16* __restrict__ qT,
                                                 const u16* __restrict__ kT,
                                                 const u16* __restrict__ vv,
                                                 u16* __restrict__ pA,
                                                 u16* __restrict__ pB,
                                                 float2* __restrict__ pml) {
    __shared__ __align__(16) u16 kbuf[2][4096];
    __shared__ __align__(16) u16 vbuf[2][4096];
    const int bh = blockIdx.y, b = bh >> 2, h = bh & 3;
    const int qb = blockIdx.x >> 1, khalf = blockIdx.x & 1;
    const int tid = threadIdx.x, w = tid >> 6, l = tid & 63;
    const int q5 = l & 31, hi = l >> 5;
    const int n0w = qb * 128 + w * 32;
    const int kbase = khalf * 2048;
    const u16* qp = qT + (size_t)bh * 262144;
    const u16* kp = kT + (size_t)bh * 262144;
    const u16* vp = vv + (size_t)bh * 262144;

    // Q fragments (B-operand: col = q5, k-elems 8hi+j, 4 d-steps)
    const u16* qrow = qp + (size_t)(n0w + q5) * 64 + 8 * hi;
    bf16x8 qf[4];
    qf[0] = *(const bf16x8*)(qrow);
    qf[1] = *(const bf16x8*)(qrow + 16);
    qf[2] = *(const bf16x8*)(qrow + 32);
    qf[3] = *(const bf16x8*)(qrow + 48);

    // staging geometry: wave w stages rows 16w..16w+15 (2 issues of 8 rows)
    const int pr = l >> 3, pc = l & 7;
    const int gswz = ((pc ^ pr) << 3);                 // pre-swizzled source chunk
    const u16* kgl = kp + (size_t)(kbase + 16 * w + pr) * 64 + gswz;
    const u16* vgl = vp + (size_t)(16 * w + pr) * 4096 + kbase + gswz;
    const int lbase = 1024 * w;
    const int ksw = q5 & 7;

    f32x16 o0, o1, zz;
#pragma unroll
    for (int r = 0; r < 16; ++r) { o0[r] = 0.f; o1[r] = 0.f; zz[r] = 0.f; }
    float mrun = -3.0e38f, lsum = 0.f;

#define STAGE(BUF, IT)                                                        \
    {                                                                         \
        const u16* kt_ = kgl + (size_t)(IT) * 4096;                           \
        const u16* vt_ = vgl + (size_t)(IT) * 64;                             \
        gld16(kt_,         &kbuf[BUF][lbase]);                                \
        gld16(kt_ + 512,   &kbuf[BUF][lbase + 512]);                          \
        gld16(vt_,         &vbuf[BUF][lbase]);                                \
        gld16(vt_ + 32768, &vbuf[BUF][lbase + 512]);                          \
    }

    STAGE(0, 0);
    __syncthreads();

    int cur = 0;
    for (int it = 0; it < 32; ++it) {
        if (it < 31) STAGE(cur ^ 1, it + 1);
        const u16* kb = &kbuf[cur][q5 * 64];
        const u16* vb = &vbuf[cur][q5 * 64];
        // ---- QK^T: s0 = S[q5][keys 0..31], s1 = keys 32..63 (exp2 domain) --
        f32x16 s0, s1;
        __builtin_amdgcn_s_setprio(1);
        {
            int ch = ((hi) ^ ksw) << 3;
            s0 = MFMA32(*(const bf16x8*)(kb + ch),        qf[0], zz, 0, 0, 0);
            s1 = MFMA32(*(const bf16x8*)(kb + 2048 + ch), qf[0], zz, 0, 0, 0);
        }
#pragma unroll
        for (int st = 1; st < 4; ++st) {
            int ch = ((hi + 2 * st) ^ ksw) << 3;
            s0 = MFMA32(*(const bf16x8*)(kb + ch),        qf[st], s0, 0, 0, 0);
            s1 = MFMA32(*(const bf16x8*)(kb + 2048 + ch), qf[st], s1, 0, 0, 0);
        }
        __builtin_amdgcn_s_setprio(0);
        // ---- online softmax, in-register (depth-5 trees) ----
        float t[16];
#pragma unroll
        for (int r = 0; r < 16; ++r) t[r] = fmaxf(s0[r], s1[r]);
#pragma unroll
        for (int k = 8; k; k >>= 1)
#pragma unroll
            for (int i = 0; i < 16 && i < k; ++i) t[i] = fmaxf(t[i], t[i + k]);
        float pm = t[0];
        pm = fmaxf(pm, __shfl_xor(pm, 32, 64));
        if (!__all(pm - mrun <= THRX)) {   // defer-rescale (T13)
            float mnew = fmaxf(mrun, pm);
            float al = EXPX(mrun - mnew);
            mrun = mnew;
            lsum *= al;
#pragma unroll
            for (int r = 0; r < 16; ++r) {
                float ar = __shfl(al, (r & 3) + 8 * (r >> 2) + 4 * hi, 64);
                o0[r] *= ar; o1[r] *= ar;
            }
        }
#pragma unroll
        for (int r = 0; r < 16; ++r) s0[r] = EXPX(s0[r] - mrun);
#pragma unroll
        for (int r = 0; r < 16; ++r) s1[r] = EXPX(s1[r] - mrun);
        float u[16];
#pragma unroll
        for (int r = 0; r < 16; ++r) u[r] = s0[r] + s1[r];
#pragma unroll
        for (int k = 8; k; k >>= 1)
#pragma unroll
            for (int i = 0; i < 16 && i < k; ++i) u[i] += u[i + k];
        float rs = u[0];
        rs += __shfl_xor(rs, 32, 64);
        lsum += rs;
        // ---- P -> bf16 A-fragments (cvt_pk + permlane32_swap) ----
        unsigned c0 = cvtpk(s0[0], s0[1]),   c1 = cvtpk(s0[2], s0[3]);
        unsigned c2 = cvtpk(s0[4], s0[5]),   c3 = cvtpk(s0[6], s0[7]);
        unsigned c4 = cvtpk(s0[8], s0[9]),   c5 = cvtpk(s0[10], s0[11]);
        unsigned c6 = cvtpk(s0[12], s0[13]), c7 = cvtpk(s0[14], s0[15]);
        unsigned d0 = cvtpk(s1[0], s1[1]),   d1 = cvtpk(s1[2], s1[3]);
        unsigned d2 = cvtpk(s1[4], s1[5]),   d3 = cvtpk(s1[6], s1[7]);
        unsigned d4 = cvtpk(s1[8], s1[9]),   d5 = cvtpk(s1[10], s1[11]);
        unsigned d6 = cvtpk(s1[12], s1[13]), d7 = cvtpk(s1[14], s1[15]);
        unsigned x0a, x0b, y0a, y0b, x1a, x1b, y1a, y1b;
        unsigned x2a, x2b, y2a, y2b, x3a, x3b, y3a, y3b;
        plswap(c0, c2, x0a, x0b); plswap(c1, c3, y0a, y0b);
        plswap(c4, c6, x1a, x1b); plswap(c5, c7, y1a, y1b);
        plswap(d0, d2, x2a, x2b); plswap(d1, d3, y2a, y2b);
        plswap(d4, d6, x3a, x3b); plswap(d5, d7, y3a, y3b);
        union { unsigned u[4]; bf16x8 v; } pa0, pa1, pa2, pa3;
        pa0.u[0] = x0a; pa0.u[1] = y0a; pa0.u[2] = x0b; pa0.u[3] = y0b;
        pa1.u[0] = x1a; pa1.u[1] = y1a; pa1.u[2] = x1b; pa1.u[3] = y1b;
        pa2.u[0] = x2a; pa2.u[1] = y2a; pa2.u[2] = x2b; pa2.u[3] = y2b;
        pa3.u[0] = x3a; pa3.u[1] = y3a; pa3.u[2] = x3b; pa3.u[3] = y3b;
        // ---- PV: O[q][d] += P * V ----
        __builtin_amdgcn_s_setprio(1);
        {
            int ch0 = ((0 + hi) ^ ksw) << 3;
            int ch1 = ((2 + hi) ^ ksw) << 3;
            int ch2 = ((4 + hi) ^ ksw) << 3;
            int ch3 = ((6 + hi) ^ ksw) << 3;
            o0 = MFMA32(pa0.v, *(const bf16x8*)(vb + ch0),        o0, 0, 0, 0);
            o1 = MFMA32(pa0.v, *(const bf16x8*)(vb + 2048 + ch0), o1, 0, 0, 0);
            o0 = MFMA32(pa1.v, *(const bf16x8*)(vb + ch1),        o0, 0, 0, 0);
            o1 = MFMA32(pa1.v, *(const bf16x8*)(vb + 2048 + ch1), o1, 0, 0, 0);
            o0 = MFMA32(pa2.v, *(const bf16x8*)(vb + ch2),        o0, 0, 0, 0);
            o1 = MFMA32(pa2.v, *(const bf16x8*)(vb + 2048 + ch2), o1, 0, 0, 0);
            o0 = MFMA32(pa3.v, *(const bf16x8*)(vb + ch3),        o0, 0, 0, 0);
            o1 = MFMA32(pa3.v, *(const bf16x8*)(vb + 2048 + ch3), o1, 0, 0, 0);
        }
        __builtin_amdgcn_s_setprio(0);
        __syncthreads();
        cur ^= 1;
    }
#undef STAGE
    // ---- epilogue: UNNORMALIZED O -> partial buffer; (m,l) -> pml ----------
    u16* ob = (khalf ? pB : pA) + ((size_t)b * 4096 + n0w) * 256 + h * 64 + q5;
#pragma unroll
    for (int r = 0; r < 16; ++r) {
        int qo = (r & 3) + 8 * (r >> 2) + 4 * hi;
        ob[(size_t)qo * 256]      = f2bf(o0[r]);
        ob[(size_t)qo * 256 + 32] = f2bf(o1[r]);
    }
    if (hi == 0)
        pml[((size_t)khalf * 16 + bh) * 4096 + n0w + q5] = make_float2(mrun, lsum);
}

// ---------------- Kernel 5b: split-K combine -> oT --------------------------
// 65536 rows x 64 d. Block 256: 32 rows, 8 threads/row x 8 d each.
__global__ void __launch_bounds__(256) combine_k(const u16* __restrict__ pA,
                                                 const u16* __restrict__ pB,
                                                 const float2* __restrict__ pml,
                                                 u16* __restrict__ oT) {
    int idx = blockIdx.x * 32 + (threadIdx.x >> 3);  // global row
    int bh = idx >> 12, n = idx & 4095;
    int d0 = (threadIdx.x & 7) * 8;
    float2 mA = pml[(size_t)bh * 4096 + n];
    float2 mB = pml[(size_t)(16 + bh) * 4096 + n];
    float M = fmaxf(mA.x, mB.x);
    float a0 = EXPX(mA.x - M), a1 = EXPX(mB.x - M);
    float linv = 1.f / (mA.y * a0 + mB.y * a1);
    a0 *= linv; a1 *= linv;
    size_t off = (size_t)idx * 256 + ((bh & 3) * 64 - ((size_t)(bh & 3) << 18)) + d0;
    // idx*256 = (bh*4096+n)*256 = b*4194304 + (bh&3)*1048576 + n*256; we need
    // b*4194304 + n*256 + h*64. Compute directly instead:
    {
        int b = bh >> 2, h = bh & 3;
        off = ((size_t)b * 4096 + n) * 256 + h * 64 + d0;
    }
    uint4 A = *(const uint4*)(pA + off);
    uint4 B = *(const uint4*)(pB + off);
    unsigned out[4];
#pragma unroll
    for (int j = 0; j < 4; ++j) {
        unsigned ua = ((const unsigned*)&A)[j], ub = ((const unsigned*)&B)[j];
        float lo = bfu2f(ua << 16) * a0 + bfu2f(ub << 16) * a1;
        float hh = bfu2f(ua & 0xffff0000u) * a0 + bfu2f(ub & 0xffff0000u) * a1;
        out[j] = cvtpk(lo, hh);
    }
    *(uint4*)(oT + off) = *(uint4*)out;
}

// ---------------- Kernel 6: proj GEMM + bias + residual --------------------
__global__ void __launch_bounds__(256) proj_gemm_k(const u16* __restrict__ wp,
                                                   const float* __restrict__ pb,
                                                   const u16* __restrict__ oT,
                                                   const float* __restrict__ x,
                                                   float* __restrict__ out) {
    int b  = blockIdx.z;
    int w  = threadIdx.x >> 6, l = threadIdx.x & 63;
    int lr = l & 15, lg = l >> 4;
    int m0 = blockIdx.y * 64 + w * 16;
    int n0 = blockIdx.x * 64;
    f32x4 acc[4];
#pragma unroll
    for (int g = 0; g < 4; g++) acc[g] = (f32x4){0.f, 0.f, 0.f, 0.f};
    const u16* ap = wp + (size_t)(m0 + lr) * 256 + 8 * lg;
    const u16* bp = oT + ((size_t)b * 4096 + n0 + lr) * 256 + 8 * lg;
#pragma unroll 2
    for (int k0 = 0; k0 < 256; k0 += 32) {
        bf16x8 a = *reinterpret_cast<const bf16x8*>(ap + k0);
#pragma unroll
        for (int g = 0; g < 4; g++) {
            bf16x8 bb = *reinterpret_cast<const bf16x8*>(bp + (size_t)g * 16 * 256 + k0);
            acc[g] = __builtin_amdgcn_mfma_f32_16x16x32_bf16(a, bb, acc[g], 0, 0, 0);
        }
    }
#pragma unroll
    for (int g = 0; g < 4; g++)
#pragma unroll
        for (int j = 0; j < 4; j++) {
            int o = m0 + lg * 4 + j;
            int n = n0 + g * 16 + lr;
            size_t idx = ((size_t)b * 256 + o) * 4096 + n;
            out[idx] = x[idx] + pb[o] + acc[g][j];
        }
}

// ---------------------------------------------------------------------------
extern "C" void kernel_launch(void* const* d_in, const int* in_sizes, int n_in,
                              void* d_out, int out_size, void* d_ws, size_t ws_size,
                              hipStream_t stream) {
    const float* x      = (const float*)d_in[0];
    const float* gn_w   = (const float*)d_in[1];
    const float* gn_b   = (const float*)d_in[2];
    const float* qkv_w  = (const float*)d_in[3];
    const float* qkv_b  = (const float*)d_in[4];
    const float* proj_w = (const float*)d_in[5];
    const float* proj_b = (const float*)d_in[6];
    float* out = (float*)d_out;

    char* ws = (char*)d_ws;
    float* stats = (float*)(ws + 0);            //      256 B
    u16* wq  = (u16*)(ws + 256);                //  393216 B
    u16* wp  = (u16*)(ws + 393472);             //  131072 B
    u16* xnT = (u16*)(ws + 524544);             // 8388608 B  [b][n][256]
    u16* qT  = (u16*)(ws + 8913152);            // 8388608 B  [bh][n][64]
    u16* kT  = (u16*)(ws + 17301760);           // 8388608 B  [bh][n][64]
    u16* vv  = (u16*)(ws + 25690368);           // 8388608 B  [bh][64][n]
    u16* oT  = (u16*)(ws + 34078976);           // 8388608 B  [b][n][256] (= pA)
    float* part = (float*)(ws + 42467584);      //     2048 B
    u16* pB  = (u16*)(ws + 42469632);           // 8388608 B  partial half-1
    float2* pml = (float2*)(ws + 50858240);     // 1048576 B  [2][16][4096]

    gn_stats1_k<<<dim3(256), dim3(256), 0, stream>>>(x, part);
    gn_stats2_k<<<dim3(1), dim3(64), 0, stream>>>(part, stats);
    convw_k<<<dim3(768), dim3(256), 0, stream>>>(qkv_w, proj_w, wq, wp);
    gnorm_t_k<<<dim3(128, 8, 4), dim3(32, 8), 0, stream>>>(x, stats, gn_w, gn_b, xnT);
    qkv_gemm_k<<<dim3(64, 12, 4), dim3(256), 0, stream>>>(wq, qkv_b, xnT, qT, kT, vv);
    attn_k<<<dim3(64, 16), dim3(256), 0, stream>>>(qT, kT, vv, oT, pB, pml);
    combine_k<<<dim3(2048), dim3(256), 0, stream>>>(oT, pB, pml, oT);
    proj_gemm_k<<<dim3(64, 4, 4), dim3(256), 0, stream>>>(wp, proj_b, oT, x, out);
}

// Round 8
// 252.464 us; speedup vs baseline: 3.0628x; 1.0544x over previous
//
#include <hip/hip_runtime.h>
#include <hip/hip_bf16.h>

typedef unsigned short u16;
typedef __attribute__((ext_vector_type(4))) float f32x4;
typedef __attribute__((ext_vector_type(16))) float f32x16;
typedef __attribute__((ext_vector_type(8))) __bf16 bf16x8;
typedef __attribute__((ext_vector_type(2))) unsigned u32x2;

#define DEVI static __device__ __forceinline__
#define MFMA32 __builtin_amdgcn_mfma_f32_32x32x16_bf16

#if defined(__has_builtin)
#if __has_builtin(__builtin_amdgcn_exp2f)
#define HAVE_EXP2 1
#endif
#endif

#ifdef HAVE_EXP2
#define EXPX(x) __builtin_amdgcn_exp2f(x)
#define QSCALE 0.18033688011112042f /* 0.125 * log2(e): softmax in exp2 domain */
#else
#define EXPX(x) __expf(x)
#define QSCALE 0.125f
#endif

DEVI u16 f2bf(float f) {
    union { float f; unsigned u; } v; v.f = f;
    unsigned r = v.u + 0x7fffu + ((v.u >> 16) & 1u);
    return (u16)(r >> 16);
}

DEVI float bfu2f(unsigned lo16shifted) {  // takes already-positioned 32b pattern
    union { unsigned u; float f; } v; v.u = lo16shifted; return v.f;
}

DEVI unsigned cvtpk(float lo, float hi_) {
    unsigned r;
    asm("v_cvt_pk_bf16_f32 %0, %1, %2" : "=v"(r) : "v"(lo), "v"(hi_));
    return r;
}

DEVI void plswap(unsigned a, unsigned b, unsigned& o0, unsigned& o1) {
#if defined(__has_builtin) && __has_builtin(__builtin_amdgcn_permlane32_swap)
    u32x2 r = __builtin_amdgcn_permlane32_swap(a, b, false, false);
    o0 = r[0]; o1 = r[1];
#else
    unsigned xa = (unsigned)__shfl_xor((int)a, 32, 64);
    unsigned xb = (unsigned)__shfl_xor((int)b, 32, 64);
    bool hi = (threadIdx.x & 32) != 0;
    o0 = hi ? xb : a;
    o1 = hi ? b : xa;
#endif
}

// async global->LDS, 16B per lane, LDS dest = uniform base + lane*16
DEVI void gld16(const u16* g, u16* l) {
    __builtin_amdgcn_global_load_lds(
        (const __attribute__((address_space(1))) unsigned int*)g,
        (__attribute__((address_space(3))) unsigned int*)l, 16, 0, 0);
}

// ---------------- Kernel 1a: GroupNorm partial sums (256 blocks) ------------
__global__ void __launch_bounds__(256) gn_stats1_k(const float* __restrict__ x,
                                                   float* __restrict__ part) {
    int bid = blockIdx.x;            // 32 bg x 8 segments
    int bg = bid >> 3, seg = bid & 7;
    const float4* p = reinterpret_cast<const float4*>(x + (size_t)bg * 131072 + seg * 16384);
    float s = 0.f, s2 = 0.f;
    for (int i = threadIdx.x; i < 4096; i += 256) {
        float4 v = p[i];
        s  += v.x + v.y + v.z + v.w;
        s2 += v.x * v.x + v.y * v.y + v.z * v.z + v.w * v.w;
    }
    for (int off = 32; off; off >>= 1) {
        s  += __shfl_down(s,  off, 64);
        s2 += __shfl_down(s2, off, 64);
    }
    __shared__ float sb[8];
    int w = threadIdx.x >> 6, l = threadIdx.x & 63;
    if (l == 0) { sb[w] = s; sb[4 + w] = s2; }
    __syncthreads();
    if (threadIdx.x == 0) {
        part[bid * 2]     = sb[0] + sb[1] + sb[2] + sb[3];
        part[bid * 2 + 1] = sb[4] + sb[5] + sb[6] + sb[7];
    }
}

// ---------------- Kernel 1b: finalize stats ---------------------------------
__global__ void gn_stats2_k(const float* __restrict__ part, float* __restrict__ stats) {
    int t = threadIdx.x;
    if (t < 32) {
        float s = 0.f, s2 = 0.f;
#pragma unroll
        for (int i = 0; i < 8; i++) { s += part[(t * 8 + i) * 2]; s2 += part[(t * 8 + i) * 2 + 1]; }
        float mu  = s * (1.f / 131072.f);
        float var = s2 * (1.f / 131072.f) - mu * mu;
        stats[t * 2]     = mu;
        stats[t * 2 + 1] = rsqrtf(var + 1e-5f);
    }
}

// ---------------- Kernel 2: weights fp32 -> bf16 ----------------------------
__global__ void __launch_bounds__(256) convw_k(const float* __restrict__ qw,
                                               const float* __restrict__ pw,
                                               u16* __restrict__ wq,
                                               u16* __restrict__ wp) {
    int i = blockIdx.x * 256 + threadIdx.x;
    if (i < 196608) wq[i] = f2bf(qw[i]);
    if (i < 65536)  wp[i] = f2bf(pw[i]);
}

// ---------------- Kernel 3: normalize + transpose -> xnT[b][n][c] bf16 ------
__global__ void __launch_bounds__(256) gnorm_t_k(const float* __restrict__ x,
                                                 const float* __restrict__ stats,
                                                 const float* __restrict__ gw,
                                                 const float* __restrict__ gb,
                                                 u16* __restrict__ xnT) {
    __shared__ float tile[32][33];
    int b = blockIdx.z, c0 = blockIdx.y * 32, n0 = blockIdx.x * 32;
    int tx = threadIdx.x, ty = threadIdx.y;
    const float* xb = x + ((size_t)b * 256 + c0) * 4096 + n0;
#pragma unroll
    for (int j = 0; j < 4; j++) {
        int r = ty + 8 * j;
        tile[r][tx] = xb[(size_t)r * 4096 + tx];
    }
    __syncthreads();
    int c = c0 + tx;
    int g = c >> 5;
    float mu = stats[(b * 8 + g) * 2], rs = stats[(b * 8 + g) * 2 + 1];
    float sc = rs * gw[c];
    float sh = gb[c] - mu * sc;
    u16* o = xnT + ((size_t)b * 4096 + n0) * 256 + c;
#pragma unroll
    for (int j = 0; j < 4; j++) {
        int r = ty + 8 * j;
        float v = tile[tx][r];
        o[(size_t)r * 256] = f2bf(v * sc + sh);
    }
}

// ---------------- Kernel 4: QKV GEMM + transpose epilogue -------------------
__global__ void __launch_bounds__(256) qkv_gemm_k(const u16* __restrict__ wq,
                                                  const float* __restrict__ qkvb,
                                                  const u16* __restrict__ xnT,
                                                  u16* __restrict__ qT,
                                                  u16* __restrict__ kT,
                                                  u16* __restrict__ vv) {
    __shared__ __align__(16) u16 T[64 * 72];
    int b  = blockIdx.z;
    int w  = threadIdx.x >> 6, l = threadIdx.x & 63;
    int lr = l & 15, lg = l >> 4;
    int m0b = blockIdx.y * 64;
    int m0 = m0b + w * 16;
    int n0 = blockIdx.x * 64;
    f32x4 acc[4];
#pragma unroll
    for (int g = 0; g < 4; g++) acc[g] = (f32x4){0.f, 0.f, 0.f, 0.f};
    const u16* ap = wq + (size_t)(m0 + lr) * 256 + 8 * lg;
    const u16* bp = xnT + ((size_t)b * 4096 + n0 + lr) * 256 + 8 * lg;
#pragma unroll 2
    for (int k0 = 0; k0 < 256; k0 += 32) {
        bf16x8 a = *reinterpret_cast<const bf16x8*>(ap + k0);
#pragma unroll
        for (int g = 0; g < 4; g++) {
            bf16x8 bb = *reinterpret_cast<const bf16x8*>(bp + (size_t)g * 16 * 256 + k0);
            acc[g] = __builtin_amdgcn_mfma_f32_16x16x32_bf16(a, bb, acc[g], 0, 0, 0);
        }
    }
    int sec  = m0b >> 8;            // 0=q 1=k 2=v
    int hsec = (m0b >> 6) & 3;      // head within section
    float qs = (sec == 0) ? QSCALE : 1.f;
#pragma unroll
    for (int g = 0; g < 4; g++) {
        ushort4 pk;
#pragma unroll
        for (int j = 0; j < 4; j++) {
            int o = m0 + lg * 4 + j;
            float v = (acc[g][j] + qkvb[o]) * qs;
            ((u16*)&pk)[j] = f2bf(v);
        }
        if (sec < 2) {   // tile[n][o_local]
            *(ushort4*)&T[(g * 16 + lr) * 72 + w * 16 + lg * 4] = pk;
        } else {         // tile[o_local][n]
#pragma unroll
            for (int j = 0; j < 4; j++)
                T[(w * 16 + lg * 4 + j) * 72 + g * 16 + lr] = ((u16*)&pk)[j];
        }
    }
    __syncthreads();
    int row = threadIdx.x >> 2;
    u16* dst;
    if (sec < 2) {
        u16* base = (sec == 0 ? qT : kT);
        dst = base + ((size_t)(b * 4 + hsec) * 4096 + n0 + row) * 64;
    } else {
        dst = vv + ((size_t)(b * 4 + hsec) * 64 + row) * 4096 + n0;
    }
#pragma unroll
    for (int p = 0; p < 2; p++) {
        int c = (threadIdx.x & 3) + 4 * p;
        *(ulonglong2*)(dst + c * 8) = *(const ulonglong2*)&T[row * 72 + c * 8];
    }
}

// ---------------- Kernel 5: flash attention, split-K x2, NO-MAX softmax -----
// exp2-domain scores are bounded (|s| <~ 26 << 127) so exp2(s) cannot overflow
// f32; bf16 relative precision is exponent-invariant -> max-subtraction is
// unnecessary. Row-sums l computed on the MFMA pipe via B=ones (lane-replicated,
// reg=q-row). Partials: unnormalized O (bf16) + l (f32); combine = (A+B)/(lA+lB).
__global__ void __launch_bounds__(256, 4) attn_k(const u16* __restrict__ qT,
                                                 const u16* __restrict__ kT,
                                                 const u16* __restrict__ vv,
                                                 u16* __restrict__ pA,
                                                 u16* __restrict__ pB,
                                                 float* __restrict__ pl) {
    __shared__ __align__(16) u16 kbuf[2][4096];
    __shared__ __align__(16) u16 vbuf[2][4096];
    const int bh = blockIdx.y, b = bh >> 2, h = bh & 3;
    const int qb = blockIdx.x >> 1, khalf = blockIdx.x & 1;
    const int tid = threadIdx.x, w = tid >> 6, l = tid & 63;
    const int q5 = l & 31, hi = l >> 5;
    const int n0w = qb * 128 + w * 32;
    const int kbase = khalf * 2048;
    const u16* qp = qT + (size_t)bh * 262144;
    const u16* kp = kT + (size_t)bh * 262144;
    const u16* vp = vv + (size_t)bh * 262144;

    // Q fragments (B-operand: col = q5, k-elems 8hi+j, 4 d-steps)
    const u16* qrow = qp + (size_t)(n0w + q5) * 64 + 8 * hi;
    bf16x8 qf[4];
    qf[0] = *(const bf16x8*)(qrow);
    qf[1] = *(const bf16x8*)(qrow + 16);
    qf[2] = *(const bf16x8*)(qrow + 32);
    qf[3] = *(const bf16x8*)(qrow + 48);

    // ones vector (bf16 1.0 x8) for row-sum MFMA
    union { unsigned u[4]; bf16x8 v; } ones;
    ones.u[0] = 0x3F803F80u; ones.u[1] = 0x3F803F80u;
    ones.u[2] = 0x3F803F80u; ones.u[3] = 0x3F803F80u;

    // staging geometry: wave w stages rows 16w..16w+15 (2 issues of 8 rows)
    const int pr = l >> 3, pc = l & 7;
    const int gswz = ((pc ^ pr) << 3);                 // pre-swizzled source chunk
    const u16* kgl = kp + (size_t)(kbase + 16 * w + pr) * 64 + gswz;
    const u16* vgl = vp + (size_t)(16 * w + pr) * 4096 + kbase + gswz;
    const int lbase = 1024 * w;
    const int ksw = q5 & 7;

    f32x16 o0, o1, lacc, zz;
#pragma unroll
    for (int r = 0; r < 16; ++r) { o0[r] = 0.f; o1[r] = 0.f; lacc[r] = 0.f; zz[r] = 0.f; }

#define STAGE(BUF, IT)                                                        \
    {                                                                         \
        const u16* kt_ = kgl + (size_t)(IT) * 4096;                           \
        const u16* vt_ = vgl + (size_t)(IT) * 64;                             \
        gld16(kt_,         &kbuf[BUF][lbase]);                                \
        gld16(kt_ + 512,   &kbuf[BUF][lbase + 512]);                          \
        gld16(vt_,         &vbuf[BUF][lbase]);                                \
        gld16(vt_ + 32768, &vbuf[BUF][lbase + 512]);                          \
    }

    STAGE(0, 0);
    __syncthreads();

    int cur = 0;
    for (int it = 0; it < 32; ++it) {
        if (it < 31) STAGE(cur ^ 1, it + 1);
        const u16* kb = &kbuf[cur][q5 * 64];
        const u16* vb = &vbuf[cur][q5 * 64];
        // ---- QK^T: s0 = S[q5][keys 0..31], s1 = keys 32..63 (exp2 domain) --
        f32x16 s0, s1;
        __builtin_amdgcn_s_setprio(1);
        {
            int ch = ((hi) ^ ksw) << 3;
            s0 = MFMA32(*(const bf16x8*)(kb + ch),        qf[0], zz, 0, 0, 0);
            s1 = MFMA32(*(const bf16x8*)(kb + 2048 + ch), qf[0], zz, 0, 0, 0);
        }
#pragma unroll
        for (int st = 1; st < 4; ++st) {
            int ch = ((hi + 2 * st) ^ ksw) << 3;
            s0 = MFMA32(*(const bf16x8*)(kb + ch),        qf[st], s0, 0, 0, 0);
            s1 = MFMA32(*(const bf16x8*)(kb + 2048 + ch), qf[st], s1, 0, 0, 0);
        }
        __builtin_amdgcn_s_setprio(0);
        // ---- softmax numerator, no max subtraction ----
#pragma unroll
        for (int r = 0; r < 16; ++r) s0[r] = EXPX(s0[r]);
#pragma unroll
        for (int r = 0; r < 16; ++r) s1[r] = EXPX(s1[r]);
        // ---- P -> bf16 A-fragments (cvt_pk + permlane32_swap) ----
        unsigned c0 = cvtpk(s0[0], s0[1]),   c1 = cvtpk(s0[2], s0[3]);
        unsigned c2 = cvtpk(s0[4], s0[5]),   c3 = cvtpk(s0[6], s0[7]);
        unsigned c4 = cvtpk(s0[8], s0[9]),   c5 = cvtpk(s0[10], s0[11]);
        unsigned c6 = cvtpk(s0[12], s0[13]), c7 = cvtpk(s0[14], s0[15]);
        unsigned d0 = cvtpk(s1[0], s1[1]),   d1 = cvtpk(s1[2], s1[3]);
        unsigned d2 = cvtpk(s1[4], s1[5]),   d3 = cvtpk(s1[6], s1[7]);
        unsigned d4 = cvtpk(s1[8], s1[9]),   d5 = cvtpk(s1[10], s1[11]);
        unsigned d6 = cvtpk(s1[12], s1[13]), d7 = cvtpk(s1[14], s1[15]);
        unsigned x0a, x0b, y0a, y0b, x1a, x1b, y1a, y1b;
        unsigned x2a, x2b, y2a, y2b, x3a, x3b, y3a, y3b;
        plswap(c0, c2, x0a, x0b); plswap(c1, c3, y0a, y0b);
        plswap(c4, c6, x1a, x1b); plswap(c5, c7, y1a, y1b);
        plswap(d0, d2, x2a, x2b); plswap(d1, d3, y2a, y2b);
        plswap(d4, d6, x3a, x3b); plswap(d5, d7, y3a, y3b);
        union { unsigned u[4]; bf16x8 v; } pa0, pa1, pa2, pa3;
        pa0.u[0] = x0a; pa0.u[1] = y0a; pa0.u[2] = x0b; pa0.u[3] = y0b;
        pa1.u[0] = x1a; pa1.u[1] = y1a; pa1.u[2] = x1b; pa1.u[3] = y1b;
        pa2.u[0] = x2a; pa2.u[1] = y2a; pa2.u[2] = x2b; pa2.u[3] = y2b;
        pa3.u[0] = x3a; pa3.u[1] = y3a; pa3.u[2] = x3b; pa3.u[3] = y3b;
        // ---- PV + row-sum (on MFMA pipe): O += P*V ; l += P*ones ----
        __builtin_amdgcn_s_setprio(1);
        {
            int ch0 = ((0 + hi) ^ ksw) << 3;
            int ch1 = ((2 + hi) ^ ksw) << 3;
            int ch2 = ((4 + hi) ^ ksw) << 3;
            int ch3 = ((6 + hi) ^ ksw) << 3;
            o0 = MFMA32(pa0.v, *(const bf16x8*)(vb + ch0),        o0, 0, 0, 0);
            o1 = MFMA32(pa0.v, *(const bf16x8*)(vb + 2048 + ch0), o1, 0, 0, 0);
            lacc = MFMA32(pa0.v, ones.v, lacc, 0, 0, 0);
            o0 = MFMA32(pa1.v, *(const bf16x8*)(vb + ch1),        o0, 0, 0, 0);
            o1 = MFMA32(pa1.v, *(const bf16x8*)(vb + 2048 + ch1), o1, 0, 0, 0);
            lacc = MFMA32(pa1.v, ones.v, lacc, 0, 0, 0);
            o0 = MFMA32(pa2.v, *(const bf16x8*)(vb + ch2),        o0, 0, 0, 0);
            o1 = MFMA32(pa2.v, *(const bf16x8*)(vb + 2048 + ch2), o1, 0, 0, 0);
            lacc = MFMA32(pa2.v, ones.v, lacc, 0, 0, 0);
            o0 = MFMA32(pa3.v, *(const bf16x8*)(vb + ch3),        o0, 0, 0, 0);
            o1 = MFMA32(pa3.v, *(const bf16x8*)(vb + 2048 + ch3), o1, 0, 0, 0);
            lacc = MFMA32(pa3.v, ones.v, lacc, 0, 0, 0);
        }
        __builtin_amdgcn_s_setprio(0);
        __syncthreads();
        cur ^= 1;
    }
#undef STAGE
    // ---- epilogue: raw O -> partial buffer; l -> pl -------------------------
    u16* ob = (khalf ? pB : pA) + ((size_t)b * 4096 + n0w) * 256 + h * 64 + q5;
#pragma unroll
    for (int r = 0; r < 16; ++r) {
        int qo = (r & 3) + 8 * (r >> 2) + 4 * hi;
        ob[(size_t)qo * 256]      = f2bf(o0[r]);
        ob[(size_t)qo * 256 + 32] = f2bf(o1[r]);
    }
    if (q5 == 0) {
        float* pd = pl + ((size_t)khalf * 16 + bh) * 4096 + n0w;
#pragma unroll
        for (int r = 0; r < 16; ++r) {
            int qo = (r & 3) + 8 * (r >> 2) + 4 * hi;
            pd[qo] = lacc[r];
        }
    }
}

// ---------------- Kernel 5b: split-K combine -> oT --------------------------
// 65536 rows x 64 d. Block 256: 32 rows, 8 threads/row x 8 d each.
__global__ void __launch_bounds__(256) combine_k(const u16* __restrict__ pA,
                                                 const u16* __restrict__ pB,
                                                 const float* __restrict__ pl,
                                                 u16* __restrict__ oT) {
    int idx = blockIdx.x * 32 + (threadIdx.x >> 3);  // global row
    int bh = idx >> 12, n = idx & 4095;
    int d0 = (threadIdx.x & 7) * 8;
    float lA = pl[(size_t)bh * 4096 + n];
    float lB = pl[(size_t)(16 + bh) * 4096 + n];
    float linv = 1.f / (lA + lB);
    int b = bh >> 2, h = bh & 3;
    size_t off = ((size_t)b * 4096 + n) * 256 + h * 64 + d0;
    uint4 A = *(const uint4*)(pA + off);
    uint4 B = *(const uint4*)(pB + off);
    unsigned out[4];
#pragma unroll
    for (int j = 0; j < 4; ++j) {
        unsigned ua = ((const unsigned*)&A)[j], ub = ((const unsigned*)&B)[j];
        float lo = (bfu2f(ua << 16) + bfu2f(ub << 16)) * linv;
        float hh = (bfu2f(ua & 0xffff0000u) + bfu2f(ub & 0xffff0000u)) * linv;
        out[j] = cvtpk(lo, hh);
    }
    *(uint4*)(oT + off) = *(uint4*)out;
}

// ---------------- Kernel 6: proj GEMM + bias + residual --------------------
__global__ void __launch_bounds__(256) proj_gemm_k(const u16* __restrict__ wp,
                                                   const float* __restrict__ pb,
                                                   const u16* __restrict__ oT,
                                                   const float* __restrict__ x,
                                                   float* __restrict__ out) {
    int b  = blockIdx.z;
    int w  = threadIdx.x >> 6, l = threadIdx.x & 63;
    int lr = l & 15, lg = l >> 4;
    int m0 = blockIdx.y * 64 + w * 16;
    int n0 = blockIdx.x * 64;
    f32x4 acc[4];
#pragma unroll
    for (int g = 0; g < 4; g++) acc[g] = (f32x4){0.f, 0.f, 0.f, 0.f};
    const u16* ap = wp + (size_t)(m0 + lr) * 256 + 8 * lg;
    const u16* bp = oT + ((size_t)b * 4096 + n0 + lr) * 256 + 8 * lg;
#pragma unroll 2
    for (int k0 = 0; k0 < 256; k0 += 32) {
        bf16x8 a = *reinterpret_cast<const bf16x8*>(ap + k0);
#pragma unroll
        for (int g = 0; g < 4; g++) {
            bf16x8 bb = *reinterpret_cast<const bf16x8*>(bp + (size_t)g * 16 * 256 + k0);
            acc[g] = __builtin_amdgcn_mfma_f32_16x16x32_bf16(a, bb, acc[g], 0, 0, 0);
        }
    }
#pragma unroll
    for (int g = 0; g < 4; g++)
#pragma unroll
        for (int j = 0; j < 4; j++) {
            int o = m0 + lg * 4 + j;
            int n = n0 + g * 16 + lr;
            size_t idx = ((size_t)b * 256 + o) * 4096 + n;
            out[idx] = x[idx] + pb[o] + acc[g][j];
        }
}

// ---------------------------------------------------------------------------
extern "C" void kernel_launch(void* const* d_in, const int* in_sizes, int n_in,
                              void* d_out, int out_size, void* d_ws, size_t ws_size,
                              hipStream_t stream) {
    const float* x      = (const float*)d_in[0];
    const float* gn_w   = (const float*)d_in[1];
    const float* gn_b   = (const float*)d_in[2];
    const float* qkv_w  = (const float*)d_in[3];
    const float* qkv_b  = (const float*)d_in[4];
    const float* proj_w = (const float*)d_in[5];
    const float* proj_b = (const float*)d_in[6];
    float* out = (float*)d_out;

    char* ws = (char*)d_ws;
    float* stats = (float*)(ws + 0);            //      256 B
    u16* wq  = (u16*)(ws + 256);                //  393216 B
    u16* wp  = (u16*)(ws + 393472);             //  131072 B
    u16* xnT = (u16*)(ws + 524544);             // 8388608 B  [b][n][256]
    u16* qT  = (u16*)(ws + 8913152);            // 8388608 B  [bh][n][64]
    u16* kT  = (u16*)(ws + 17301760);           // 8388608 B  [bh][n][64]
    u16* vv  = (u16*)(ws + 25690368);           // 8388608 B  [bh][64][n]
    u16* oT  = (u16*)(ws + 34078976);           // 8388608 B  [b][n][256] (= pA)
    float* part = (float*)(ws + 42467584);      //     2048 B
    u16* pB  = (u16*)(ws + 42469632);           // 8388608 B  partial half-1
    float* pl = (float*)(ws + 50858240);        //  524288 B  [2][16][4096]

    gn_stats1_k<<<dim3(256), dim3(256), 0, stream>>>(x, part);
    gn_stats2_k<<<dim3(1), dim3(64), 0, stream>>>(part, stats);
    convw_k<<<dim3(768), dim3(256), 0, stream>>>(qkv_w, proj_w, wq, wp);
    gnorm_t_k<<<dim3(128, 8, 4), dim3(32, 8), 0, stream>>>(x, stats, gn_w, gn_b, xnT);
    qkv_gemm_k<<<dim3(64, 12, 4), dim3(256), 0, stream>>>(wq, qkv_b, xnT, qT, kT, vv);
    attn_k<<<dim3(64, 16), dim3(256), 0, stream>>>(qT, kT, vv, oT, pB, pl);
    combine_k<<<dim3(2048), dim3(256), 0, stream>>>(oT, pB, pl, oT);
    proj_gemm_k<<<dim3(64, 4, 4), dim3(256), 0, stream>>>(wp, proj_b, oT, x, out);
}